// Round 1
// 424.079 us; speedup vs baseline: 1.0534x; 1.0534x over previous
//
#include <hip/hip_runtime.h>

typedef unsigned short u16;
typedef __attribute__((ext_vector_type(8))) short bf16x8;   // 8 bf16 = 4 VGPRs (MFMA A/B frag)
typedef __attribute__((ext_vector_type(4))) float floatx4;  // MFMA C/D frag

__device__ __forceinline__ float bf2f(u16 h) {
  return __uint_as_float(((unsigned int)h) << 16);
}
__device__ __forceinline__ u16 f2bf(float f) {
  unsigned int u = __float_as_uint(f);
  u += 0x7fffu + ((u >> 16) & 1u);  // RNE
  return (u16)(u >> 16);
}
// cheaper round-half-up (same 0.5 ulp bound) for the attention P pack
__device__ __forceinline__ u16 f2bf_hu(float f) {
  return (u16)((__float_as_uint(f) + 0x8000u) >> 16);
}
// raw v_exp_f32: computes 2^x (softmax runs in log2 domain; log2e folded into Q scale)
__device__ __forceinline__ float exp2fast(float x) {
  float r;
  asm("v_exp_f32 %0, %1" : "=v"(r) : "v"(x));
  return r;
}
// probe[0] is freqs_cos[0] == 1.0f: fp32 low u16 = 0x0000, bf16 = 0x3F80.
__device__ __forceinline__ bool is_f32(const u16* probe) { return probe[0] == 0; }

// async global->LDS, 16B per lane. LDS dest must be wave-uniform base + lane*16.
#define GLOAD_LDS16(gsrc, ldst)                                                        \
  __builtin_amdgcn_global_load_lds(                                                    \
      (const __attribute__((address_space(1))) unsigned int*)(gsrc),                   \
      (__attribute__((address_space(3))) unsigned int*)(ldst), 16, 0, 0)

// ------------- convert any input buffer (fp32 or bf16 per probe) -> bf16 --------------
__global__ __launch_bounds__(256) void cvt_to_bf16(const void* __restrict__ in,
                                                   u16* __restrict__ out, int n,
                                                   const u16* __restrict__ probe) {
  int i = (blockIdx.x * 256 + threadIdx.x) * 8;
  if (i >= n) return;
  if (is_f32(probe)) {
    const float* f = (const float*)in;
    uint4 o;
    o.x = (unsigned)f2bf(f[i + 0]) | ((unsigned)f2bf(f[i + 1]) << 16);
    o.y = (unsigned)f2bf(f[i + 2]) | ((unsigned)f2bf(f[i + 3]) << 16);
    o.z = (unsigned)f2bf(f[i + 4]) | ((unsigned)f2bf(f[i + 5]) << 16);
    o.w = (unsigned)f2bf(f[i + 6]) | ((unsigned)f2bf(f[i + 7]) << 16);
    *(uint4*)(out + i) = o;
  } else {
    *(uint4*)(out + i) = *(const uint4*)((const u16*)in + i);
  }
}

// ---------- transpose+convert: in (R,C) fp32/bf16 per probe -> out (C,R) bf16 ---------
__global__ __launch_bounds__(256) void transpose_cvt(const void* __restrict__ in,
                                                     u16* __restrict__ out,
                                                     int R, int C,
                                                     const u16* __restrict__ probe) {
  __shared__ u16 tile[32][33];
  int bx = blockIdx.x * 32;  // input col base
  int by = blockIdx.y * 32;  // input row base
  int tx = threadIdx.x & 31, ty = threadIdx.x >> 5;  // 32 x 8
  if (is_f32(probe)) {
    const float* f = (const float*)in;
    for (int i = 0; i < 32; i += 8)
      tile[ty + i][tx] = f2bf(f[(size_t)(by + ty + i) * C + (bx + tx)]);
  } else {
    const u16* u = (const u16*)in;
    for (int i = 0; i < 32; i += 8)
      tile[ty + i][tx] = u[(size_t)(by + ty + i) * C + (bx + tx)];
  }
  __syncthreads();
  for (int i = 0; i < 32; i += 8)
    out[(size_t)(bx + ty + i) * R + (by + tx)] = tile[tx][ty + i];
}

// ---------------- GEMM: C = A[M,K] * BT[N,K]^T, dtype-aware output (out projection) ---
// 128x128 tile, 256 threads (4 waves, 2x2), BK=32, mfma 16x16x32 bf16,
// global_load_lds width-16 staging (m97 structure). Writes fp32 if probe says fp32.
__global__ __launch_bounds__(256) void gemm_bt(const u16* __restrict__ A,
                                               const u16* __restrict__ BT,
                                               void* __restrict__ C,
                                               int M, int N, int K,
                                               const u16* __restrict__ probe) {
  __shared__ __align__(16) u16 As[128 * 32];
  __shared__ __align__(16) u16 Bs[128 * 32];
  const int m0 = blockIdx.y * 128, n0 = blockIdx.x * 128;
  const int t = threadIdx.x;
  const int wave = t >> 6, lane = t & 63;
  const int wm = (wave >> 1) * 64, wn = (wave & 1) * 64;
  const int quad = lane >> 4, l16 = lane & 15;
  const bool f32o = is_f32(probe);
  floatx4 acc[4][4];
  for (int i = 0; i < 4; ++i)
    for (int j = 0; j < 4; ++j) acc[i][j] = (floatx4){0.f, 0.f, 0.f, 0.f};

  for (int kt = 0; kt < K; kt += 32) {
    __syncthreads();
    for (int i = 0; i < 2; ++i) {
      int e = (i * 256 + t) * 8;
      int r = e >> 5, c = e & 31;
      GLOAD_LDS16(A + (size_t)(m0 + r) * K + kt + c, As + e);
      GLOAD_LDS16(BT + (size_t)(n0 + r) * K + kt + c, Bs + e);
    }
    __syncthreads();
    bf16x8 af[4], bfr[4];
    for (int i = 0; i < 4; ++i)
      af[i] = *(const bf16x8*)&As[(wm + i * 16 + l16) * 32 + quad * 8];
    for (int j = 0; j < 4; ++j)
      bfr[j] = *(const bf16x8*)&Bs[(wn + j * 16 + l16) * 32 + quad * 8];
    for (int i = 0; i < 4; ++i)
      for (int j = 0; j < 4; ++j)
        acc[i][j] = __builtin_amdgcn_mfma_f32_16x16x32_bf16(af[i], bfr[j], acc[i][j], 0, 0, 0);
  }
  // epilogue: C row = quad*4+reg, col = l16 (verified m89/m91 layout)
  for (int i = 0; i < 4; ++i) {
    int rbase = m0 + wm + i * 16 + quad * 4;
    for (int j = 0; j < 4; ++j) {
      int col = n0 + wn + j * 16 + l16;
      if (f32o) {
        float* Cf = (float*)C;
        for (int r = 0; r < 4; ++r) Cf[(size_t)(rbase + r) * N + col] = acc[i][j][r];
      } else {
        u16* Ch = (u16*)C;
        for (int r = 0; r < 4; ++r) Ch[(size_t)(rbase + r) * N + col] = f2bf(acc[i][j][r]);
      }
    }
  }
}

// ------------- fused split GEMM: cols [0,nsplit) -> Ca with interleaved RoPE*oscale,
//               cols [nsplit,N) -> Cb plain row-major (vmode 0) or V^T scatter (vmode 1)
// B rows are one contiguous [N][K] buffer (weight transposes placed adjacently in ws).
__global__ __launch_bounds__(256) void gemm_fused(const u16* __restrict__ A,
                                                  const u16* __restrict__ BT,
                                                  u16* __restrict__ Ca, int sa,
                                                  u16* __restrict__ Cb, int sb,
                                                  int M, int N, int K, int nsplit,
                                                  int vmode,
                                                  const u16* __restrict__ fc,
                                                  const u16* __restrict__ fs,
                                                  float oscale) {
  __shared__ __align__(16) u16 As[128 * 32];
  __shared__ __align__(16) u16 Bs[128 * 32];
  const int m0 = blockIdx.y * 128, n0 = blockIdx.x * 128;
  const int t = threadIdx.x;
  const int wave = t >> 6, lane = t & 63;
  const int wm = (wave >> 1) * 64, wn = (wave & 1) * 64;
  const int quad = lane >> 4, l16 = lane & 15;
  floatx4 acc[4][4];
  for (int i = 0; i < 4; ++i)
    for (int j = 0; j < 4; ++j) acc[i][j] = (floatx4){0.f, 0.f, 0.f, 0.f};

  for (int kt = 0; kt < K; kt += 32) {
    __syncthreads();
    for (int i = 0; i < 2; ++i) {
      int e = (i * 256 + t) * 8;
      int r = e >> 5, c = e & 31;
      GLOAD_LDS16(A + (size_t)(m0 + r) * K + kt + c, As + e);
      GLOAD_LDS16(BT + (size_t)(n0 + r) * K + kt + c, Bs + e);
    }
    __syncthreads();
    bf16x8 af[4], bfr[4];
    for (int i = 0; i < 4; ++i)
      af[i] = *(const bf16x8*)&As[(wm + i * 16 + l16) * 32 + quad * 8];
    for (int j = 0; j < 4; ++j)
      bfr[j] = *(const bf16x8*)&Bs[(wn + j * 16 + l16) * 32 + quad * 8];
    for (int i = 0; i < 4; ++i)
      for (int j = 0; j < 4; ++j)
        acc[i][j] = __builtin_amdgcn_mfma_f32_16x16x32_bf16(af[i], bfr[j], acc[i][j], 0, 0, 0);
  }

  if (n0 < nsplit) {
    // ---- RoPE epilogue (col pairs live in adjacent lanes; tiles are 128 = head dim) --
    const bool odd = (l16 & 1);
    for (int i = 0; i < 4; ++i) {
      int rbase = m0 + wm + i * 16 + quad * 4;
      for (int j = 0; j < 4; ++j) {
        int col = n0 + wn + j * 16 + l16;
        int p = (wn + j * 16 + l16) >> 1;  // pair index within head (0..63)
        for (int r = 0; r < 4; ++r) {
          int srow = (rbase + r) & 2047;  // token index (M = B*2048)
          float c = bf2f(fc[srow * 64 + p]);
          float sn = bf2f(fs[srow * 64 + p]);
          float v = acc[i][j][r];
          float pv = __shfl_xor(v, 1);
          float o = fmaf(v, c, odd ? pv * sn : -pv * sn);
          Ca[(size_t)(rbase + r) * sa + col] = f2bf(o * oscale);
        }
      }
    }
  } else if (vmode == 0) {
    // ---- plain row-major into Cb ----
    for (int i = 0; i < 4; ++i) {
      int rbase = m0 + wm + i * 16 + quad * 4;
      for (int j = 0; j < 4; ++j) {
        int col = n0 - nsplit + wn + j * 16 + l16;
        for (int r = 0; r < 4; ++r)
          Cb[(size_t)(rbase + r) * sb + col] = f2bf(acc[i][j][r]);
      }
    }
  } else {
    // ---- V^T scatter: Cb is (B,H,128,S); 4 tokens contiguous per lane -> ushort4 ----
    for (int i = 0; i < 4; ++i) {
      int token0 = m0 + wm + i * 16 + quad * 4;  // 2048-aligned tiles: same b for r=0..3
      for (int j = 0; j < 4; ++j) {
        int ch = n0 - nsplit + wn + j * 16 + l16;  // h*128 + d
        size_t base = (((size_t)((token0 >> 11) * 16 + (ch >> 7)) * 128 + (ch & 127)) << 11) +
                      (token0 & 2047);
        ushort4 pk;
        pk.x = f2bf(acc[i][j][0]);
        pk.y = f2bf(acc[i][j][1]);
        pk.z = f2bf(acc[i][j][2]);
        pk.w = f2bf(acc[i][j][3]);
        *(ushort4*)(Cb + base) = pk;
      }
    }
  }
}

// ---------------- RMSNorm over rows of 512, in place (bf16) ---------------------------
__global__ __launch_bounds__(256) void rmsnorm_kernel(u16* __restrict__ t,
                                                      const u16* __restrict__ w) {
  int row = blockIdx.x * 4 + (threadIdx.x >> 6);
  int lane = threadIdx.x & 63;
  u16* xr = t + (size_t)row * 512;
  float v[8];
  float ss = 0.f;
  for (int i = 0; i < 8; ++i) {
    v[i] = bf2f(xr[lane + i * 64]);
    ss += v[i] * v[i];
  }
  for (int d = 32; d > 0; d >>= 1) ss += __shfl_xor(ss, d);
  float r = rsqrtf(ss * (1.f / 512.f) + 1e-6f);
  for (int i = 0; i < 8; ++i) xr[lane + i * 64] = f2bf(v[i] * r * bf2f(w[lane + i * 64]));
}

// ---------------- Flash attention (causal), bf16 MFMA, log2-domain softmax ------------
// q PRE-SCALED by (1/sqrt(128))*log2e in gemm_fused => scores are log2-domain; exp via
// raw v_exp_f32 (2^x). k: (B,S,H*128). vt: (B,H,128,S). o: (B,S,H*128).
// 1D grid of 1024; decode gives each CU's 4 co-resident blocks qb {31-j, j, 23-j, 8+j}
// = uniform 66 K-tiles/CU (was 52..80 with the 2D grid). Deferred-max (THR=8 log2,
// P<=256) skips alpha-rescale on the ~90% of tiles where the running max is stable.
__global__ __launch_bounds__(256) void attn_kernel(const u16* __restrict__ q,
                                                   const u16* __restrict__ k,
                                                   const u16* __restrict__ vt,
                                                   u16* __restrict__ o) {
  const int S = 2048;
  __shared__ __align__(16) u16 Kt[64 * 128];   // [key][chunk8 ^ (key&15)]
  __shared__ __align__(16) u16 Vt[128 * 64];   // [d][granule8 ^ (d&7)]
  __shared__ __align__(16) u16 P[4][16][64];   // [row][granule8 ^ (row&7)]
  const int t = threadIdx.x;
  const int w = t >> 6, lane = t & 63;
  const int quad = lane >> 4, l16 = lane & 15;
  // balance decode: n -> (bh, qb); co-resident set {n, n+256, n+512, n+768} sums to 66
  const int n = blockIdx.x;
  const int bh = n & 31;
  const int jj = (n >> 5) & 7;
  const int kk = n >> 8;
  int qb;
  if (kk == 0)      qb = 31 - jj;   // heaviest dispatched first
  else if (kk == 1) qb = jj;
  else if (kk == 2) qb = 23 - jj;
  else              qb = 8 + jj;
  const int b = bh >> 4, h = bh & 15;
  const int q0 = qb * 64 + w * 16;

  // Q fragments (A layout: m=l16, k=quad*8+j), 4 dim-chunks of 32
  const u16* qbase = q + ((size_t)(b * S + q0 + l16)) * 2048 + h * 128;
  bf16x8 qf[4];
  for (int c = 0; c < 4; ++c) qf[c] = *(const bf16x8*)(qbase + c * 32 + quad * 8);

  const u16* kbase = k + (size_t)b * S * 2048 + h * 128;
  const u16* vtb = vt + (size_t)bh * 128 * S;

  const int ksrow = t >> 4, ksc = t & 15;  // K staging decode
  const int vsrow = t >> 3, vsc = t & 7;   // V staging decode

  float m_i[4], l_i[4];
  floatx4 acc[8];
  for (int r = 0; r < 4; ++r) { m_i[r] = -1e30f; l_i[r] = 0.f; }
  for (int nd = 0; nd < 8; ++nd) acc[nd] = (floatx4){0.f, 0.f, 0.f, 0.f};

  const int kmax = q0 + 15;      // last unmasked key for this wave
  const int qbase64 = qb * 64;   // diagonal step base
  for (int kb = 0; kb <= qbase64; kb += 64) {
    const bool diag = (kb == qbase64);
    __syncthreads();  // all waves done reading Kt/Vt from previous step
    for (int j = 0; j < 4; ++j) {
      int row = j * 16 + ksrow;
      GLOAD_LDS16(kbase + (size_t)(kb + row) * 2048 + (ksc ^ (row & 15)) * 8,
                  Kt + (size_t)(row * 16 + ksc) * 8);
    }
    for (int j = 0; j < 4; ++j) {
      int row = j * 32 + vsrow;
      GLOAD_LDS16(vtb + (size_t)row * S + kb + ((vsc ^ (row & 7)) * 8),
                  Vt + (size_t)(row * 8 + vsc) * 8);
    }
    __syncthreads();  // staging drained

    // ---- scores (log2 domain; masks only on diagonal step) ----
    floatx4 s[4];
    if (!diag) {
      for (int ns = 0; ns < 4; ++ns) {
        s[ns] = (floatx4){0.f, 0.f, 0.f, 0.f};
        for (int c = 0; c < 4; ++c) {
          bf16x8 kf = *(const bf16x8*)&Kt[(ns * 16 + l16) * 128 + ((c * 4 + quad) ^ l16) * 8];
          s[ns] = __builtin_amdgcn_mfma_f32_16x16x32_bf16(qf[c], kf, s[ns], 0, 0, 0);
        }
      }
    } else {
      for (int ns = 0; ns < 4; ++ns) {
        if (kb + ns * 16 <= kmax) {
          s[ns] = (floatx4){0.f, 0.f, 0.f, 0.f};
          for (int c = 0; c < 4; ++c) {
            bf16x8 kf = *(const bf16x8*)&Kt[(ns * 16 + l16) * 128 + ((c * 4 + quad) ^ l16) * 8];
            s[ns] = __builtin_amdgcn_mfma_f32_16x16x32_bf16(qf[c], kf, s[ns], 0, 0, 0);
          }
          int key = kb + ns * 16 + l16;
          for (int r = 0; r < 4; ++r)
            s[ns][r] = (key > q0 + quad * 4 + r) ? -1e30f : s[ns][r];
        } else {
          s[ns] = (floatx4){-1e30f, -1e30f, -1e30f, -1e30f};
        }
      }
    }
    // ---- online softmax, deferred max (score row = quad*4+r, col = l16) ----
    float tmax[4];
    for (int r = 0; r < 4; ++r) {
      float v = fmaxf(fmaxf(s[0][r], s[1][r]), fmaxf(s[2][r], s[3][r]));
      for (int d = 1; d < 16; d <<= 1) v = fmaxf(v, __shfl_xor(v, d));
      tmax[r] = v;
    }
    bool grow = (tmax[0] > m_i[0] + 8.f) || (tmax[1] > m_i[1] + 8.f) ||
                (tmax[2] > m_i[2] + 8.f) || (tmax[3] > m_i[3] + 8.f);
    if (__any(grow)) {  // uniform branch; taken on first tile + rare max growth
      for (int r = 0; r < 4; ++r) {
        float mn = fmaxf(m_i[r], tmax[r]);
        float alpha = exp2fast(m_i[r] - mn);
        m_i[r] = mn;
        l_i[r] *= alpha;
        for (int nd = 0; nd < 8; ++nd)
          for (int rr = 0; rr < 1; ++rr) acc[nd][r] *= alpha;
      }
    }
    for (int ns = 0; ns < 4; ++ns)
      for (int r = 0; r < 4; ++r) s[ns][r] = exp2fast(s[ns][r] - m_i[r]);
    for (int r = 0; r < 4; ++r) {
      float v = s[0][r] + s[1][r] + s[2][r] + s[3][r];
      for (int d = 1; d < 16; d <<= 1) v += __shfl_xor(v, d);
      l_i[r] += v;
    }
    // ---- P to LDS (C layout -> A layout; swizzled granules; per-wave private) ----
    for (int ns = 0; ns < 4; ++ns)
      for (int r = 0; r < 4; ++r) {
        int row = quad * 4 + r;
        P[w][row][(((ns * 2 + (l16 >> 3)) ^ (row & 7)) << 3) | (l16 & 7)] = f2bf_hu(s[ns][r]);
      }
    // ---- PV: O += P(16x64) * V(64x128), both operands from swizzled LDS ----
    for (int kc = 0; kc < 2; ++kc) {
      if (!diag || kb + kc * 32 <= kmax) {
        bf16x8 pa = *(const bf16x8*)&P[w][l16][((kc * 4 + quad) ^ (l16 & 7)) * 8];
        for (int nd = 0; nd < 8; ++nd) {
          int d = nd * 16 + l16;
          bf16x8 vf = *(const bf16x8*)&Vt[(d * 8 + ((kc * 4 + quad) ^ (d & 7))) * 8];
          acc[nd] = __builtin_amdgcn_mfma_f32_16x16x32_bf16(pa, vf, acc[nd], 0, 0, 0);
        }
      }
    }
  }
  // ---- epilogue ----
  u16* ob = o + ((size_t)(b * S + q0 + quad * 4)) * 2048 + h * 128;
  for (int r = 0; r < 4; ++r) {
    float inv = 1.f / l_i[r];
    for (int nd = 0; nd < 8; ++nd)
      ob[(size_t)r * 2048 + nd * 16 + l16] = f2bf(acc[nd][r] * inv);
  }
}

// ------------------------------------ launcher ---------------------------------------
// Workspace: 83 MiB, lifetime-aliased. Input dtype (fp32 vs bf16) detected on-device
// from freqs_cos[0].
extern "C" void kernel_launch(void* const* d_in, const int* in_sizes, int n_in,
                              void* d_out, int out_size, void* d_ws, size_t ws_size,
                              hipStream_t stream) {
  const void* x    = d_in[0];  // (2,2048,2048)
  const void* fcos = d_in[1];  // (2048,64)
  const void* fsin = d_in[2];
  const void* wkv  = d_in[3];  // (2048,512)
  const void* wnr  = d_in[4];  // (512,)
  const void* wku  = d_in[5];  // (512,2048)
  const void* wvu  = d_in[6];  // (512,2048)
  const void* wq   = d_in[7];  // (2048,2048)
  const void* wo   = d_in[8];  // (2048,2048)
  const u16* probe = (const u16*)fcos;

  const size_t MB = 1u << 20;
  char* ws = (char*)d_ws;
  u16* xc    = (u16*)(ws);             // 16 MiB x bf16; dead after fused Q+KV
  u16* vtb   = (u16*)(ws);             //   ... then V^T (B,H,128,S), written by K+V gemm
  u16* qb    = (u16*)(ws + 16 * MB);   // 16 MiB q (rope'd, pre-scaled); dead after attn
  u16* kb    = (u16*)(ws + 32 * MB);   // 16 MiB k (rope'd)
  u16* ab    = (u16*)(ws + 48 * MB);   // 16 MiB attention output
  u16* lat   = (u16*)(ws + 64 * MB);   // 4 MiB kv latent
  u16* wqT   = (u16*)(ws + 68 * MB);   // 8 MiB; contiguous with wkvT -> fused B [2560,2048]
  u16* woT   = (u16*)(ws + 68 * MB);   //   ... then w_out^T (after Q+KV gemm)
  u16* wkvT  = (u16*)(ws + 76 * MB);   // 2 MiB
  u16* wkT   = (u16*)(ws + 78 * MB);   // 2 MiB; contiguous with wvT -> fused B [4096,512]
  u16* wvT   = (u16*)(ws + 80 * MB);   // 2 MiB
  u16* fcosc = (u16*)(ws + 82 * MB);   // 256 KiB
  u16* fsinc = (u16*)(ws + 82 * MB + 256 * 1024);
  u16* wnrc  = (u16*)(ws + 82 * MB + 512 * 1024);  // 1 KiB  (total < 83 MiB)

  // 1/sqrt(128) * log2(e): softmax runs in log2 domain (v_exp_f32 = 2^x)
  const float QSCALE = 0.08838834764831845f * 1.4426950408889634f;
  dim3 blk(256);
  // --- convert inputs to bf16 (identity copy if already bf16) ---
  cvt_to_bf16<<<dim3(4096), blk, 0, stream>>>(x, xc, 8388608, probe);
  cvt_to_bf16<<<dim3(64), blk, 0, stream>>>(fcos, fcosc, 131072, probe);
  cvt_to_bf16<<<dim3(64), blk, 0, stream>>>(fsin, fsinc, 131072, probe);
  cvt_to_bf16<<<dim3(1), blk, 0, stream>>>(wnr, wnrc, 512, probe);

  // --- weight transposes for the fused Q+KV gemm (B rows: wqT then wkvT, contiguous) --
  transpose_cvt<<<dim3(64, 64), blk, 0, stream>>>(wq, wqT, 2048, 2048, probe);
  transpose_cvt<<<dim3(16, 64), blk, 0, stream>>>(wkv, wkvT, 2048, 512, probe);

  // --- fused Q (rope, pre-scaled) + KV-compress (plain -> lat): N=2560, 640 blocks ----
  gemm_fused<<<dim3(20, 32), blk, 0, stream>>>(xc, wqT, qb, 2048, lat, 512,
                                               4096, 2560, 2048, 2048, 0,
                                               fcosc, fsinc, QSCALE);
  rmsnorm_kernel<<<dim3(1024), blk, 0, stream>>>(lat, wnrc);

  // --- fused K (rope) + V (direct V^T scatter): N=4096, 1024 blocks (full capacity) ---
  transpose_cvt<<<dim3(64, 16), blk, 0, stream>>>(wku, wkT, 512, 2048, probe);
  transpose_cvt<<<dim3(64, 16), blk, 0, stream>>>(wvu, wvT, 512, 2048, probe);
  gemm_fused<<<dim3(32, 32), blk, 0, stream>>>(lat, wkT, kb, 2048, vtb, 0,
                                               4096, 4096, 512, 2048, 1,
                                               fcosc, fsinc, 1.0f);

  // --- w_out^T into dead wqT slot ---
  transpose_cvt<<<dim3(64, 64), blk, 0, stream>>>(wo, woT, 2048, 2048, probe);

  // --- causal flash attention (balanced 1D grid) ---
  attn_kernel<<<dim3(1024), blk, 0, stream>>>(qb, kb, vtb, ab);

  // --- output projection straight into d_out (dtype-aware epilogue) ---
  gemm_bt<<<dim3(16, 32), blk, 0, stream>>>(ab, woT, d_out, 4096, 2048, 2048, probe);
}

// Round 2
// 394.365 us; speedup vs baseline: 1.1328x; 1.0753x over previous
//
#include <hip/hip_runtime.h>

typedef unsigned short u16;
typedef __attribute__((ext_vector_type(8))) short bf16x8;   // 8 bf16 = 4 VGPRs (MFMA A/B frag)
typedef __attribute__((ext_vector_type(4))) float floatx4;  // MFMA C/D frag

__device__ __forceinline__ float bf2f(u16 h) {
  return __uint_as_float(((unsigned int)h) << 16);
}
__device__ __forceinline__ u16 f2bf(float f) {
  unsigned int u = __float_as_uint(f);
  u += 0x7fffu + ((u >> 16) & 1u);  // RNE
  return (u16)(u >> 16);
}
// cheaper round-half-up (same 0.5 ulp bound) for the attention P pack
__device__ __forceinline__ u16 f2bf_hu(float f) {
  return (u16)((__float_as_uint(f) + 0x8000u) >> 16);
}
// raw v_exp_f32: computes 2^x (softmax runs in log2 domain; log2e folded into Q scale)
__device__ __forceinline__ float exp2fast(float x) {
  float r;
  asm("v_exp_f32 %0, %1" : "=v"(r) : "v"(x));
  return r;
}
// probe[0] is freqs_cos[0] == 1.0f: fp32 low u16 = 0x0000, bf16 = 0x3F80.
__device__ __forceinline__ bool is_f32(const u16* probe) { return probe[0] == 0; }

// async global->LDS, 16B per lane. LDS dest must be wave-uniform base + lane*16.
#define GLOAD_LDS16(gsrc, ldst)                                                        \
  __builtin_amdgcn_global_load_lds(                                                    \
      (const __attribute__((address_space(1))) unsigned int*)(gsrc),                   \
      (__attribute__((address_space(3))) unsigned int*)(ldst), 16, 0, 0)

// ------------- convert any input buffer (fp32 or bf16 per probe) -> bf16 --------------
__global__ __launch_bounds__(256) void cvt_to_bf16(const void* __restrict__ in,
                                                   u16* __restrict__ out, int n,
                                                   const u16* __restrict__ probe) {
  int i = (blockIdx.x * 256 + threadIdx.x) * 8;
  if (i >= n) return;
  if (is_f32(probe)) {
    const float* f = (const float*)in;
    uint4 o;
    o.x = (unsigned)f2bf(f[i + 0]) | ((unsigned)f2bf(f[i + 1]) << 16);
    o.y = (unsigned)f2bf(f[i + 2]) | ((unsigned)f2bf(f[i + 3]) << 16);
    o.z = (unsigned)f2bf(f[i + 4]) | ((unsigned)f2bf(f[i + 5]) << 16);
    o.w = (unsigned)f2bf(f[i + 6]) | ((unsigned)f2bf(f[i + 7]) << 16);
    *(uint4*)(out + i) = o;
  } else {
    *(uint4*)(out + i) = *(const uint4*)((const u16*)in + i);
  }
}

// ---------- transpose+convert: in (R,C) fp32/bf16 per probe -> out (C,R) bf16 ---------
__global__ __launch_bounds__(256) void transpose_cvt(const void* __restrict__ in,
                                                     u16* __restrict__ out,
                                                     int R, int C,
                                                     const u16* __restrict__ probe) {
  __shared__ u16 tile[32][33];
  int bx = blockIdx.x * 32;  // input col base
  int by = blockIdx.y * 32;  // input row base
  int tx = threadIdx.x & 31, ty = threadIdx.x >> 5;  // 32 x 8
  if (is_f32(probe)) {
    const float* f = (const float*)in;
    for (int i = 0; i < 32; i += 8)
      tile[ty + i][tx] = f2bf(f[(size_t)(by + ty + i) * C + (bx + tx)]);
  } else {
    const u16* u = (const u16*)in;
    for (int i = 0; i < 32; i += 8)
      tile[ty + i][tx] = u[(size_t)(by + ty + i) * C + (bx + tx)];
  }
  __syncthreads();
  for (int i = 0; i < 32; i += 8)
    out[(size_t)(bx + ty + i) * R + (by + tx)] = tile[tx][ty + i];
}

// ---------------- GEMM: C = A[M,K] * BT[N,K]^T, dtype-aware output (out projection) ---
// 128x128 tile, 256 threads (4 waves, 2x2), BK=32, mfma 16x16x32 bf16,
// global_load_lds width-16 staging (m97 structure). Writes fp32 if probe says fp32.
__global__ __launch_bounds__(256) void gemm_bt(const u16* __restrict__ A,
                                               const u16* __restrict__ BT,
                                               void* __restrict__ C,
                                               int M, int N, int K,
                                               const u16* __restrict__ probe) {
  __shared__ __align__(16) u16 As[128 * 32];
  __shared__ __align__(16) u16 Bs[128 * 32];
  const int m0 = blockIdx.y * 128, n0 = blockIdx.x * 128;
  const int t = threadIdx.x;
  const int wave = t >> 6, lane = t & 63;
  const int wm = (wave >> 1) * 64, wn = (wave & 1) * 64;
  const int quad = lane >> 4, l16 = lane & 15;
  const bool f32o = is_f32(probe);
  floatx4 acc[4][4];
  for (int i = 0; i < 4; ++i)
    for (int j = 0; j < 4; ++j) acc[i][j] = (floatx4){0.f, 0.f, 0.f, 0.f};

  for (int kt = 0; kt < K; kt += 32) {
    __syncthreads();
    for (int i = 0; i < 2; ++i) {
      int e = (i * 256 + t) * 8;
      int r = e >> 5, c = e & 31;
      GLOAD_LDS16(A + (size_t)(m0 + r) * K + kt + c, As + e);
      GLOAD_LDS16(BT + (size_t)(n0 + r) * K + kt + c, Bs + e);
    }
    __syncthreads();
    bf16x8 af[4], bfr[4];
    for (int i = 0; i < 4; ++i)
      af[i] = *(const bf16x8*)&As[(wm + i * 16 + l16) * 32 + quad * 8];
    for (int j = 0; j < 4; ++j)
      bfr[j] = *(const bf16x8*)&Bs[(wn + j * 16 + l16) * 32 + quad * 8];
    for (int i = 0; i < 4; ++i)
      for (int j = 0; j < 4; ++j)
        acc[i][j] = __builtin_amdgcn_mfma_f32_16x16x32_bf16(af[i], bfr[j], acc[i][j], 0, 0, 0);
  }
  // epilogue: C row = quad*4+reg, col = l16 (verified m89/m91 layout)
  for (int i = 0; i < 4; ++i) {
    int rbase = m0 + wm + i * 16 + quad * 4;
    for (int j = 0; j < 4; ++j) {
      int col = n0 + wn + j * 16 + l16;
      if (f32o) {
        float* Cf = (float*)C;
        for (int r = 0; r < 4; ++r) Cf[(size_t)(rbase + r) * N + col] = acc[i][j][r];
      } else {
        u16* Ch = (u16*)C;
        for (int r = 0; r < 4; ++r) Ch[(size_t)(rbase + r) * N + col] = f2bf(acc[i][j][r]);
      }
    }
  }
}

// ------------- fused split GEMM: cols [0,nsplit) -> Ca with interleaved RoPE*oscale,
//               cols [nsplit,N) -> Cb plain row-major (vmode 0) or V^T scatter (vmode 1)
// B rows are one contiguous [N][K] buffer (weight transposes placed adjacently in ws).
__global__ __launch_bounds__(256) void gemm_fused(const u16* __restrict__ A,
                                                  const u16* __restrict__ BT,
                                                  u16* __restrict__ Ca, int sa,
                                                  u16* __restrict__ Cb, int sb,
                                                  int M, int N, int K, int nsplit,
                                                  int vmode,
                                                  const u16* __restrict__ fc,
                                                  const u16* __restrict__ fs,
                                                  float oscale) {
  __shared__ __align__(16) u16 As[128 * 32];
  __shared__ __align__(16) u16 Bs[128 * 32];
  const int m0 = blockIdx.y * 128, n0 = blockIdx.x * 128;
  const int t = threadIdx.x;
  const int wave = t >> 6, lane = t & 63;
  const int wm = (wave >> 1) * 64, wn = (wave & 1) * 64;
  const int quad = lane >> 4, l16 = lane & 15;
  floatx4 acc[4][4];
  for (int i = 0; i < 4; ++i)
    for (int j = 0; j < 4; ++j) acc[i][j] = (floatx4){0.f, 0.f, 0.f, 0.f};

  for (int kt = 0; kt < K; kt += 32) {
    __syncthreads();
    for (int i = 0; i < 2; ++i) {
      int e = (i * 256 + t) * 8;
      int r = e >> 5, c = e & 31;
      GLOAD_LDS16(A + (size_t)(m0 + r) * K + kt + c, As + e);
      GLOAD_LDS16(BT + (size_t)(n0 + r) * K + kt + c, Bs + e);
    }
    __syncthreads();
    bf16x8 af[4], bfr[4];
    for (int i = 0; i < 4; ++i)
      af[i] = *(const bf16x8*)&As[(wm + i * 16 + l16) * 32 + quad * 8];
    for (int j = 0; j < 4; ++j)
      bfr[j] = *(const bf16x8*)&Bs[(wn + j * 16 + l16) * 32 + quad * 8];
    for (int i = 0; i < 4; ++i)
      for (int j = 0; j < 4; ++j)
        acc[i][j] = __builtin_amdgcn_mfma_f32_16x16x32_bf16(af[i], bfr[j], acc[i][j], 0, 0, 0);
  }

  if (n0 < nsplit) {
    // ---- RoPE epilogue (col pairs live in adjacent lanes; tiles are 128 = head dim) --
    const bool odd = (l16 & 1);
    for (int i = 0; i < 4; ++i) {
      int rbase = m0 + wm + i * 16 + quad * 4;
      for (int j = 0; j < 4; ++j) {
        int col = n0 + wn + j * 16 + l16;
        int p = (wn + j * 16 + l16) >> 1;  // pair index within head (0..63)
        for (int r = 0; r < 4; ++r) {
          int srow = (rbase + r) & 2047;  // token index (M = B*2048)
          float c = bf2f(fc[srow * 64 + p]);
          float sn = bf2f(fs[srow * 64 + p]);
          float v = acc[i][j][r];
          float pv = __shfl_xor(v, 1);
          float o = fmaf(v, c, odd ? pv * sn : -pv * sn);
          Ca[(size_t)(rbase + r) * sa + col] = f2bf(o * oscale);
        }
      }
    }
  } else if (vmode == 0) {
    // ---- plain row-major into Cb ----
    for (int i = 0; i < 4; ++i) {
      int rbase = m0 + wm + i * 16 + quad * 4;
      for (int j = 0; j < 4; ++j) {
        int col = n0 - nsplit + wn + j * 16 + l16;
        for (int r = 0; r < 4; ++r)
          Cb[(size_t)(rbase + r) * sb + col] = f2bf(acc[i][j][r]);
      }
    }
  } else {
    // ---- V^T scatter: Cb is (B,H,128,S); 4 tokens contiguous per lane -> ushort4 ----
    for (int i = 0; i < 4; ++i) {
      int token0 = m0 + wm + i * 16 + quad * 4;  // 2048-aligned tiles: same b for r=0..3
      for (int j = 0; j < 4; ++j) {
        int ch = n0 - nsplit + wn + j * 16 + l16;  // h*128 + d
        size_t base = (((size_t)((token0 >> 11) * 16 + (ch >> 7)) * 128 + (ch & 127)) << 11) +
                      (token0 & 2047);
        ushort4 pk;
        pk.x = f2bf(acc[i][j][0]);
        pk.y = f2bf(acc[i][j][1]);
        pk.z = f2bf(acc[i][j][2]);
        pk.w = f2bf(acc[i][j][3]);
        *(ushort4*)(Cb + base) = pk;
      }
    }
  }
}

// ---------------- RMSNorm over rows of 512, in place (bf16) ---------------------------
__global__ __launch_bounds__(256) void rmsnorm_kernel(u16* __restrict__ t,
                                                      const u16* __restrict__ w) {
  int row = blockIdx.x * 4 + (threadIdx.x >> 6);
  int lane = threadIdx.x & 63;
  u16* xr = t + (size_t)row * 512;
  float v[8];
  float ss = 0.f;
  for (int i = 0; i < 8; ++i) {
    v[i] = bf2f(xr[lane + i * 64]);
    ss += v[i] * v[i];
  }
  for (int d = 32; d > 0; d >>= 1) ss += __shfl_xor(ss, d);
  float r = rsqrtf(ss * (1.f / 512.f) + 1e-6f);
  for (int i = 0; i < 8; ++i) xr[lane + i * 64] = f2bf(v[i] * r * bf2f(w[lane + i * 64]));
}

// ---------------- Flash attention (causal), bf16 MFMA, log2-domain softmax ------------
// q PRE-SCALED by (1/sqrt(128))*log2e in gemm_fused => scores are log2-domain; exp via
// raw v_exp_f32 (2^x). k: (B,S,H*128). vt: (B,H,128,S). o: (B,S,H*128).
// 2D grid (x=bh, y: qb = 31-y, heaviest dispatched first) — mapping-agnostic, the
// round-1 1D "balanced" decode regressed (dispatch mapping is undefined; measured
// occupancy drop). Row sums come from a ones-column MFMA (no sum butterfly).
// Deferred-max (THR=8 log2, P<=256) skips alpha-rescale on stable tiles.
__global__ __launch_bounds__(256) void attn_kernel(const u16* __restrict__ q,
                                                   const u16* __restrict__ k,
                                                   const u16* __restrict__ vt,
                                                   u16* __restrict__ o) {
  const int S = 2048;
  __shared__ __align__(16) u16 Kt[64 * 128];   // [key][chunk8 ^ (key&15)]
  __shared__ __align__(16) u16 Vt[128 * 64];   // [d][granule8 ^ (d&7)]
  __shared__ __align__(16) u16 P[4][16][64];   // [row][granule8 ^ (row&7)]
  const int t = threadIdx.x;
  const int w = t >> 6, lane = t & 63;
  const int quad = lane >> 4, l16 = lane & 15;
  const int bh = blockIdx.x;
  const int b = bh >> 4, h = bh & 15;
  const int qb = (int)gridDim.y - 1 - (int)blockIdx.y;  // heaviest first
  const int q0 = qb * 64 + w * 16;

  // Q fragments (A layout: m=l16, k=quad*8+j), 4 dim-chunks of 32
  const u16* qbase = q + ((size_t)(b * S + q0 + l16)) * 2048 + h * 128;
  bf16x8 qf[4];
  for (int c = 0; c < 4; ++c) qf[c] = *(const bf16x8*)(qbase + c * 32 + quad * 8);

  const u16* kbase = k + (size_t)b * S * 2048 + h * 128;
  const u16* vtb = vt + (size_t)bh * 128 * S;

  const int ksrow = t >> 4, ksc = t & 15;  // K staging decode
  const int vsrow = t >> 3, vsc = t & 7;   // V staging decode

  bf16x8 onesf;  // B-operand of the row-sum MFMA: all 1.0 bf16
#pragma unroll
  for (int i = 0; i < 8; ++i) onesf[i] = (short)0x3F80;

  float m_i[4], l_i[4];
  floatx4 acc[8];
  for (int r = 0; r < 4; ++r) { m_i[r] = -1e30f; l_i[r] = 0.f; }
  for (int nd = 0; nd < 8; ++nd) acc[nd] = (floatx4){0.f, 0.f, 0.f, 0.f};

  const int kmax = q0 + 15;      // last unmasked key for this wave
  const int qbase64 = qb * 64;   // diagonal step base
  for (int kb = 0; kb <= qbase64; kb += 64) {
    const bool diag = (kb == qbase64);
    __syncthreads();  // all waves done reading Kt/Vt from previous step
    for (int j = 0; j < 4; ++j) {
      int row = j * 16 + ksrow;
      GLOAD_LDS16(kbase + (size_t)(kb + row) * 2048 + (ksc ^ (row & 15)) * 8,
                  Kt + (size_t)(row * 16 + ksc) * 8);
    }
    for (int j = 0; j < 4; ++j) {
      int row = j * 32 + vsrow;
      GLOAD_LDS16(vtb + (size_t)row * S + kb + ((vsc ^ (row & 7)) * 8),
                  Vt + (size_t)(row * 8 + vsc) * 8);
    }
    __syncthreads();  // staging drained

    // ---- scores (log2 domain; masks only on diagonal step) ----
    floatx4 s[4];
    if (!diag) {
      for (int ns = 0; ns < 4; ++ns) {
        s[ns] = (floatx4){0.f, 0.f, 0.f, 0.f};
        for (int c = 0; c < 4; ++c) {
          bf16x8 kf = *(const bf16x8*)&Kt[(ns * 16 + l16) * 128 + ((c * 4 + quad) ^ l16) * 8];
          s[ns] = __builtin_amdgcn_mfma_f32_16x16x32_bf16(qf[c], kf, s[ns], 0, 0, 0);
        }
      }
    } else {
      for (int ns = 0; ns < 4; ++ns) {
        if (kb + ns * 16 <= kmax) {
          s[ns] = (floatx4){0.f, 0.f, 0.f, 0.f};
          for (int c = 0; c < 4; ++c) {
            bf16x8 kf = *(const bf16x8*)&Kt[(ns * 16 + l16) * 128 + ((c * 4 + quad) ^ l16) * 8];
            s[ns] = __builtin_amdgcn_mfma_f32_16x16x32_bf16(qf[c], kf, s[ns], 0, 0, 0);
          }
          int key = kb + ns * 16 + l16;
          for (int r = 0; r < 4; ++r)
            s[ns][r] = (key > q0 + quad * 4 + r) ? -1e30f : s[ns][r];
        } else {
          s[ns] = (floatx4){-1e30f, -1e30f, -1e30f, -1e30f};
        }
      }
    }
    // ---- online softmax, deferred max (score row = quad*4+r, col = l16) ----
    float tmax[4];
    for (int r = 0; r < 4; ++r) {
      float v = fmaxf(fmaxf(s[0][r], s[1][r]), fmaxf(s[2][r], s[3][r]));
      for (int d = 1; d < 16; d <<= 1) v = fmaxf(v, __shfl_xor(v, d));
      tmax[r] = v;
    }
    bool grow = (tmax[0] > m_i[0] + 8.f) || (tmax[1] > m_i[1] + 8.f) ||
                (tmax[2] > m_i[2] + 8.f) || (tmax[3] > m_i[3] + 8.f);
    if (__any(grow)) {  // uniform branch; taken on first tile + rare max growth
      for (int r = 0; r < 4; ++r) {
        float mn = fmaxf(m_i[r], tmax[r]);
        float alpha = exp2fast(m_i[r] - mn);
        m_i[r] = mn;
        l_i[r] *= alpha;
        for (int nd = 0; nd < 8; ++nd) acc[nd][r] *= alpha;
      }
    }
    for (int ns = 0; ns < 4; ++ns)
      for (int r = 0; r < 4; ++r) s[ns][r] = exp2fast(s[ns][r] - m_i[r]);
    // ---- P to LDS (C layout -> A layout; swizzled granules; per-wave private) ----
    for (int ns = 0; ns < 4; ++ns)
      for (int r = 0; r < 4; ++r) {
        int row = quad * 4 + r;
        P[w][row][(((ns * 2 + (l16 >> 3)) ^ (row & 7)) << 3) | (l16 & 7)] = f2bf_hu(s[ns][r]);
      }
    // ---- PV: O += P(16x64) * V(64x128); row sums l_i via ones-MFMA (same P) ----
    floatx4 ls = (floatx4){0.f, 0.f, 0.f, 0.f};
    for (int kc = 0; kc < 2; ++kc) {
      if (!diag || kb + kc * 32 <= kmax) {
        bf16x8 pa = *(const bf16x8*)&P[w][l16][((kc * 4 + quad) ^ (l16 & 7)) * 8];
        ls = __builtin_amdgcn_mfma_f32_16x16x32_bf16(pa, onesf, ls, 0, 0, 0);
        for (int nd = 0; nd < 8; ++nd) {
          int d = nd * 16 + l16;
          bf16x8 vf = *(const bf16x8*)&Vt[(d * 8 + ((kc * 4 + quad) ^ (d & 7))) * 8];
          acc[nd] = __builtin_amdgcn_mfma_f32_16x16x32_bf16(pa, vf, acc[nd], 0, 0, 0);
        }
      }
    }
    for (int r = 0; r < 4; ++r) l_i[r] += ls[r];
  }
  // ---- epilogue ----
  u16* ob = o + ((size_t)(b * S + q0 + quad * 4)) * 2048 + h * 128;
  for (int r = 0; r < 4; ++r) {
    float inv = 1.f / l_i[r];
    for (int nd = 0; nd < 8; ++nd)
      ob[(size_t)r * 2048 + nd * 16 + l16] = f2bf(acc[nd][r] * inv);
  }
}

// ------------------------------------ launcher ---------------------------------------
// Workspace: 83 MiB, lifetime-aliased. Input dtype (fp32 vs bf16) detected on-device
// from freqs_cos[0].
extern "C" void kernel_launch(void* const* d_in, const int* in_sizes, int n_in,
                              void* d_out, int out_size, void* d_ws, size_t ws_size,
                              hipStream_t stream) {
  const void* x    = d_in[0];  // (2,2048,2048)
  const void* fcos = d_in[1];  // (2048,64)
  const void* fsin = d_in[2];
  const void* wkv  = d_in[3];  // (2048,512)
  const void* wnr  = d_in[4];  // (512,)
  const void* wku  = d_in[5];  // (512,2048)
  const void* wvu  = d_in[6];  // (512,2048)
  const void* wq   = d_in[7];  // (2048,2048)
  const void* wo   = d_in[8];  // (2048,2048)
  const u16* probe = (const u16*)fcos;

  const size_t MB = 1u << 20;
  char* ws = (char*)d_ws;
  u16* xc    = (u16*)(ws);             // 16 MiB x bf16; dead after fused Q+KV
  u16* vtb   = (u16*)(ws);             //   ... then V^T (B,H,128,S), written by K+V gemm
  u16* qb    = (u16*)(ws + 16 * MB);   // 16 MiB q (rope'd, pre-scaled); dead after attn
  u16* kb    = (u16*)(ws + 32 * MB);   // 16 MiB k (rope'd)
  u16* ab    = (u16*)(ws + 48 * MB);   // 16 MiB attention output
  u16* lat   = (u16*)(ws + 64 * MB);   // 4 MiB kv latent
  u16* wqT   = (u16*)(ws + 68 * MB);   // 8 MiB; contiguous with wkvT -> fused B [2560,2048]
  u16* woT   = (u16*)(ws + 68 * MB);   //   ... then w_out^T (after Q+KV gemm)
  u16* wkvT  = (u16*)(ws + 76 * MB);   // 2 MiB
  u16* wkT   = (u16*)(ws + 78 * MB);   // 2 MiB; contiguous with wvT -> fused B [4096,512]
  u16* wvT   = (u16*)(ws + 80 * MB);   // 2 MiB
  u16* fcosc = (u16*)(ws + 82 * MB);   // 256 KiB
  u16* fsinc = (u16*)(ws + 82 * MB + 256 * 1024);
  u16* wnrc  = (u16*)(ws + 82 * MB + 512 * 1024);  // 1 KiB  (total < 83 MiB)

  // 1/sqrt(128) * log2(e): softmax runs in log2 domain (v_exp_f32 = 2^x)
  const float QSCALE = 0.08838834764831845f * 1.4426950408889634f;
  dim3 blk(256);
  // --- convert inputs to bf16 (identity copy if already bf16) ---
  cvt_to_bf16<<<dim3(4096), blk, 0, stream>>>(x, xc, 8388608, probe);
  cvt_to_bf16<<<dim3(64), blk, 0, stream>>>(fcos, fcosc, 131072, probe);
  cvt_to_bf16<<<dim3(64), blk, 0, stream>>>(fsin, fsinc, 131072, probe);
  cvt_to_bf16<<<dim3(1), blk, 0, stream>>>(wnr, wnrc, 512, probe);

  // --- weight transposes for the fused Q+KV gemm (B rows: wqT then wkvT, contiguous) --
  transpose_cvt<<<dim3(64, 64), blk, 0, stream>>>(wq, wqT, 2048, 2048, probe);
  transpose_cvt<<<dim3(16, 64), blk, 0, stream>>>(wkv, wkvT, 2048, 512, probe);

  // --- fused Q (rope, pre-scaled) + KV-compress (plain -> lat): N=2560, 640 blocks ----
  gemm_fused<<<dim3(20, 32), blk, 0, stream>>>(xc, wqT, qb, 2048, lat, 512,
                                               4096, 2560, 2048, 2048, 0,
                                               fcosc, fsinc, QSCALE);
  rmsnorm_kernel<<<dim3(1024), blk, 0, stream>>>(lat, wnrc);

  // --- fused K (rope) + V (direct V^T scatter): N=4096, 1024 blocks (full capacity) ---
  transpose_cvt<<<dim3(64, 16), blk, 0, stream>>>(wku, wkT, 512, 2048, probe);
  transpose_cvt<<<dim3(64, 16), blk, 0, stream>>>(wvu, wvT, 512, 2048, probe);
  gemm_fused<<<dim3(32, 32), blk, 0, stream>>>(lat, wkT, kb, 2048, vtb, 0,
                                               4096, 4096, 512, 2048, 1,
                                               fcosc, fsinc, 1.0f);

  // --- w_out^T into dead wqT slot ---
  transpose_cvt<<<dim3(64, 64), blk, 0, stream>>>(wo, woT, 2048, 2048, probe);

  // --- causal flash attention (2D grid, heaviest qb dispatched first) ---
  attn_kernel<<<dim3(32, 32), blk, 0, stream>>>(qb, kb, vtb, ab);

  // --- output projection straight into d_out (dtype-aware epilogue) ---
  gemm_bt<<<dim3(16, 32), blk, 0, stream>>>(ab, woT, d_out, 4096, 2048, 2048, probe);
}

// Round 3
// 389.307 us; speedup vs baseline: 1.1475x; 1.0130x over previous
//
#include <hip/hip_runtime.h>

typedef unsigned short u16;
typedef __attribute__((ext_vector_type(8))) short bf16x8;   // 8 bf16 = 4 VGPRs (MFMA A/B frag)
typedef __attribute__((ext_vector_type(4))) float floatx4;  // MFMA C/D frag

__device__ __forceinline__ float bf2f(u16 h) {
  return __uint_as_float(((unsigned int)h) << 16);
}
__device__ __forceinline__ u16 f2bf(float f) {
  unsigned int u = __float_as_uint(f);
  u += 0x7fffu + ((u >> 16) & 1u);  // RNE
  return (u16)(u >> 16);
}
// cheaper round-half-up (same 0.5 ulp bound) for the attention P pack
__device__ __forceinline__ u16 f2bf_hu(float f) {
  return (u16)((__float_as_uint(f) + 0x8000u) >> 16);
}
// raw v_exp_f32: computes 2^x (softmax runs in log2 domain; log2e folded into Q scale)
__device__ __forceinline__ float exp2fast(float x) {
  float r;
  asm("v_exp_f32 %0, %1" : "=v"(r) : "v"(x));
  return r;
}
// probe[0] is freqs_cos[0] == 1.0f: fp32 low u16 = 0x0000, bf16 = 0x3F80.
__device__ __forceinline__ bool is_f32(const u16* probe) { return probe[0] == 0; }

// async global->LDS, 16B per lane. LDS dest must be wave-uniform base + lane*16.
#define GLOAD_LDS16(gsrc, ldst)                                                        \
  __builtin_amdgcn_global_load_lds(                                                    \
      (const __attribute__((address_space(1))) unsigned int*)(gsrc),                   \
      (__attribute__((address_space(3))) unsigned int*)(ldst), 16, 0, 0)

// ------------- convert any input buffer (fp32 or bf16 per probe) -> bf16 --------------
__global__ __launch_bounds__(256) void cvt_to_bf16(const void* __restrict__ in,
                                                   u16* __restrict__ out, int n,
                                                   const u16* __restrict__ probe) {
  int i = (blockIdx.x * 256 + threadIdx.x) * 8;
  if (i >= n) return;
  if (is_f32(probe)) {
    const float* f = (const float*)in;
    uint4 o;
    o.x = (unsigned)f2bf(f[i + 0]) | ((unsigned)f2bf(f[i + 1]) << 16);
    o.y = (unsigned)f2bf(f[i + 2]) | ((unsigned)f2bf(f[i + 3]) << 16);
    o.z = (unsigned)f2bf(f[i + 4]) | ((unsigned)f2bf(f[i + 5]) << 16);
    o.w = (unsigned)f2bf(f[i + 6]) | ((unsigned)f2bf(f[i + 7]) << 16);
    *(uint4*)(out + i) = o;
  } else {
    *(uint4*)(out + i) = *(const uint4*)((const u16*)in + i);
  }
}

// ---------- transpose+convert: in (R,C) fp32/bf16 per probe -> out (C,R) bf16 ---------
__global__ __launch_bounds__(256) void transpose_cvt(const void* __restrict__ in,
                                                     u16* __restrict__ out,
                                                     int R, int C,
                                                     const u16* __restrict__ probe) {
  __shared__ u16 tile[32][33];
  int bx = blockIdx.x * 32;  // input col base
  int by = blockIdx.y * 32;  // input row base
  int tx = threadIdx.x & 31, ty = threadIdx.x >> 5;  // 32 x 8
  if (is_f32(probe)) {
    const float* f = (const float*)in;
    for (int i = 0; i < 32; i += 8)
      tile[ty + i][tx] = f2bf(f[(size_t)(by + ty + i) * C + (bx + tx)]);
  } else {
    const u16* u = (const u16*)in;
    for (int i = 0; i < 32; i += 8)
      tile[ty + i][tx] = u[(size_t)(by + ty + i) * C + (bx + tx)];
  }
  __syncthreads();
  for (int i = 0; i < 32; i += 8)
    out[(size_t)(bx + ty + i) * R + (by + tx)] = tile[tx][ty + i];
}

// ==================== 256x256 8-wave deep-pipelined GEMM (8-phase port) ===============
// C = A[M,K] * BT[N,K]^T.  BK=64 split in two 32-halves; 4 phases per K-tile:
//   ph1: k0*mhalf0   ph2: k0*mhalf1   ph3: k1*mhalf0   ph4: k1*mhalf1
// Each phase: {ds_read 8|4 x b128; stage one 16KiB half-tile (2x global_load_lds);
//              barrier; lgkmcnt(0); setprio(1); 16 MFMA; setprio(0); barrier}.
// Stage targets (tile u):  ph1 -> (u+1).A-k1   ph2 -> (u+1).B-k1   (other buffer)
//                          ph3 -> (u+2).A-k0   ph4 -> (u+2).B-k0   (current buffer)
// Every target slot's last reader finished a full closing barrier before the issue.
// Counted vmcnt(4) (= 2 half-tiles in flight) BEFORE ph4's closing barrier; the
// barrier makes the per-wave guarantee collective. Last tile: vmcnt(0) before ph2's
// closing barrier. LDS 128 KiB dynamic (2 buf x 2 khalf x 256x32 x {A,B}).
// Granule XOR swizzle g ^= (row&3)^((row>>2)&3) on both stage-source and ds_read
// (involution; 2 lanes/bank = conflict-free).
// mode 0: plain into Ca (fp32 if probe fp32), stride sa.
// mode 1: cols [0,nsplit) RoPE*oscale -> Ca; cols [nsplit,N) plain bf16 -> Cb.
// mode 2: cols [0,nsplit) RoPE*oscale -> Ca; cols [nsplit,N) V^T scatter -> Cb (B,H,128,S).
__global__ __launch_bounds__(512, 2) void gemm8(const u16* __restrict__ A,
                                                const u16* __restrict__ BT,
                                                void* __restrict__ Ca, int sa,
                                                u16* __restrict__ Cb, int sb,
                                                int N, int K, int nsplit, int mode,
                                                const u16* __restrict__ fc,
                                                const u16* __restrict__ fs,
                                                float oscale,
                                                const u16* __restrict__ probe) {
  extern __shared__ __align__(16) u16 ldsbuf[];   // 131072 B
  u16* const AsB = ldsbuf;                        // 4 slots x 8192 u16
  u16* const BsB = ldsbuf + 32768;
#define ASLOT(b, k) (AsB + ((((b) << 1) | (k)) << 13))
#define BSLOT(b, k) (BsB + ((((b) << 1) | (k)) << 13))

  const int t = threadIdx.x;
  const int lane = t & 63, wid = t >> 6;
  const int quad = lane >> 4, l16 = lane & 15;
  const int wr = wid >> 2, wc = wid & 3;          // 2 x 4 wave grid; wave owns 128x64
  const int m0 = blockIdx.y * 256, n0 = blockIdx.x * 256;
  const int NT = K >> 6;

  const u16* const Abase = A + (size_t)m0 * K;
  const u16* const Bbase = BT + (size_t)n0 * K;

  // staging decode (per-thread constants): 2 granules of 16B per half-tile
  const int e0 = t, e1 = 512 + t;
  const int r0 = e0 >> 2, r1 = e1 >> 2;
  const int sg0 = (e0 & 3) ^ ((r0 & 3) ^ ((r0 >> 2) & 3));
  const int sg1 = (e1 & 3) ^ ((r1 & 3) ^ ((r1 >> 2) & 3));
  const u16* const sa0 = Abase + (size_t)r0 * K + sg0 * 8;
  const u16* const sa1 = Abase + (size_t)r1 * K + sg1 * 8;
  const u16* const sb0 = Bbase + (size_t)r0 * K + sg0 * 8;
  const u16* const sb1 = Bbase + (size_t)r1 * K + sg1 * 8;
#define STAGE_A(slot, kb)                      \
  do {                                         \
    GLOAD_LDS16(sa0 + (kb), (slot) + e0 * 8);  \
    GLOAD_LDS16(sa1 + (kb), (slot) + e1 * 8);  \
  } while (0)
#define STAGE_B(slot, kb)                      \
  do {                                         \
    GLOAD_LDS16(sb0 + (kb), (slot) + e0 * 8);  \
    GLOAD_LDS16(sb1 + (kb), (slot) + e1 * 8);  \
  } while (0)

  // frag read: granule offset constant per lane (row base multiple of 16)
  const int gofs = (quad ^ ((l16 & 3) ^ ((l16 >> 2) & 3))) * 8;
#define FRAG(slot, row) (*(const bf16x8*)((slot) + (row) * 32 + gofs))

#define SYNC_MID()                                          \
  __builtin_amdgcn_s_barrier();                             \
  asm volatile("s_waitcnt lgkmcnt(0)" ::: "memory");        \
  __builtin_amdgcn_sched_barrier(0)

  floatx4 acc[8][4];
#pragma unroll
  for (int i = 0; i < 8; ++i)
#pragma unroll
    for (int j = 0; j < 4; ++j) acc[i][j] = (floatx4){0.f, 0.f, 0.f, 0.f};

  // ---- prologue: tile0 all 4 halves -> buf0; tile1 k-half0 -> buf1 ----
  STAGE_A(ASLOT(0, 0), 0);
  STAGE_B(BSLOT(0, 0), 0);
  STAGE_A(ASLOT(0, 1), 32);
  STAGE_B(BSLOT(0, 1), 32);
  STAGE_A(ASLOT(1, 0), 64);
  STAGE_B(BSLOT(1, 0), 64);
  asm volatile("s_waitcnt vmcnt(4)" ::: "memory");  // tile0's 4 halves landed
  __builtin_amdgcn_s_barrier();

  bf16x8 af[4], bfr[4];
  const int arow = wr * 128 + l16;   // + mi*16 (+64 for mhalf1)
  const int brow = wc * 64 + l16;    // + nj*16

#pragma unroll 1
  for (int u = 0; u < NT; ++u) {
    const int cur = u & 1, oth = cur ^ 1;
    u16* const A0 = ASLOT(cur, 0);
    u16* const A1 = ASLOT(cur, 1);
    u16* const B0 = BSLOT(cur, 0);
    u16* const B1 = BSLOT(cur, 1);
    const bool s1 = (u + 1 < NT), s2 = (u + 2 < NT);
    const int kb1 = (u + 1) << 6, kb2 = (u + 2) << 6;

    // ---------------- phase 1: k0, mhalf0 ----------------
#pragma unroll
    for (int mi = 0; mi < 4; ++mi) af[mi] = FRAG(A0, arow + mi * 16);
#pragma unroll
    for (int nj = 0; nj < 4; ++nj) bfr[nj] = FRAG(B0, brow + nj * 16);
    if (s1) STAGE_A(ASLOT(oth, 1), kb1 + 32);
    SYNC_MID();
    __builtin_amdgcn_s_setprio(1);
#pragma unroll
    for (int mi = 0; mi < 4; ++mi)
#pragma unroll
      for (int nj = 0; nj < 4; ++nj)
        acc[mi][nj] = __builtin_amdgcn_mfma_f32_16x16x32_bf16(af[mi], bfr[nj], acc[mi][nj], 0, 0, 0);
    __builtin_amdgcn_s_setprio(0);
    __builtin_amdgcn_sched_barrier(0);
    __builtin_amdgcn_s_barrier();

    // ---------------- phase 2: k0, mhalf1 ----------------
#pragma unroll
    for (int mi = 0; mi < 4; ++mi) af[mi] = FRAG(A0, arow + 64 + mi * 16);
    if (s1) STAGE_B(BSLOT(oth, 1), kb1 + 32);
    SYNC_MID();
    __builtin_amdgcn_s_setprio(1);
#pragma unroll
    for (int mi = 0; mi < 4; ++mi)
#pragma unroll
      for (int nj = 0; nj < 4; ++nj)
        acc[mi + 4][nj] = __builtin_amdgcn_mfma_f32_16x16x32_bf16(af[mi], bfr[nj], acc[mi + 4][nj], 0, 0, 0);
    __builtin_amdgcn_s_setprio(0);
    __builtin_amdgcn_sched_barrier(0);
    if (u == NT - 1) asm volatile("s_waitcnt vmcnt(0)" ::: "memory");  // epilogue drain
    __builtin_amdgcn_s_barrier();

    // ---------------- phase 3: k1, mhalf0 ----------------
#pragma unroll
    for (int mi = 0; mi < 4; ++mi) af[mi] = FRAG(A1, arow + mi * 16);
#pragma unroll
    for (int nj = 0; nj < 4; ++nj) bfr[nj] = FRAG(B1, brow + nj * 16);
    if (s2) STAGE_A(A0, kb2);
    SYNC_MID();
    __builtin_amdgcn_s_setprio(1);
#pragma unroll
    for (int mi = 0; mi < 4; ++mi)
#pragma unroll
      for (int nj = 0; nj < 4; ++nj)
        acc[mi][nj] = __builtin_amdgcn_mfma_f32_16x16x32_bf16(af[mi], bfr[nj], acc[mi][nj], 0, 0, 0);
    __builtin_amdgcn_s_setprio(0);
    __builtin_amdgcn_sched_barrier(0);
    __builtin_amdgcn_s_barrier();

    // ---------------- phase 4: k1, mhalf1 ----------------
#pragma unroll
    for (int mi = 0; mi < 4; ++mi) af[mi] = FRAG(A1, arow + 64 + mi * 16);
    if (s2) STAGE_B(B0, kb2);
    SYNC_MID();
    __builtin_amdgcn_s_setprio(1);
#pragma unroll
    for (int mi = 0; mi < 4; ++mi)
#pragma unroll
      for (int nj = 0; nj < 4; ++nj)
        acc[mi + 4][nj] = __builtin_amdgcn_mfma_f32_16x16x32_bf16(af[mi], bfr[nj], acc[mi + 4][nj], 0, 0, 0);
    __builtin_amdgcn_s_setprio(0);
    __builtin_amdgcn_sched_barrier(0);
    // counted drain BEFORE the closing barrier -> collective guarantee for next tile
    asm volatile("s_waitcnt vmcnt(4)" ::: "memory");
    __builtin_amdgcn_s_barrier();
  }

  // ---------------- epilogue ----------------
  if (mode == 0) {
    const bool f32o = is_f32(probe);
#pragma unroll
    for (int mi = 0; mi < 8; ++mi) {
      int rbase = m0 + wr * 128 + mi * 16 + quad * 4;
#pragma unroll
      for (int nj = 0; nj < 4; ++nj) {
        int col = n0 + wc * 64 + nj * 16 + l16;
        if (f32o) {
          float* Cf = (float*)Ca;
          for (int r = 0; r < 4; ++r) Cf[(size_t)(rbase + r) * sa + col] = acc[mi][nj][r];
        } else {
          u16* Ch = (u16*)Ca;
          for (int r = 0; r < 4; ++r) Ch[(size_t)(rbase + r) * sa + col] = f2bf(acc[mi][nj][r]);
        }
      }
    }
  } else if (n0 < nsplit) {
    // RoPE epilogue: col pairs live in adjacent lanes (head dim 128)
    const bool odd = (l16 & 1);
    u16* Ch = (u16*)Ca;
#pragma unroll
    for (int mi = 0; mi < 8; ++mi) {
      int rbase = m0 + wr * 128 + mi * 16 + quad * 4;
#pragma unroll
      for (int nj = 0; nj < 4; ++nj) {
        int col = n0 + wc * 64 + nj * 16 + l16;
        int p = (col & 127) >> 1;  // pair index within head (0..63)
        for (int r = 0; r < 4; ++r) {
          int srow = (rbase + r) & 2047;  // token index (M = B*2048)
          float c = bf2f(fc[srow * 64 + p]);
          float sn = bf2f(fs[srow * 64 + p]);
          float v = acc[mi][nj][r];
          float pv = __shfl_xor(v, 1);
          float o = fmaf(v, c, odd ? pv * sn : -pv * sn);
          Ch[(size_t)(rbase + r) * sa + col] = f2bf(o * oscale);
        }
      }
    }
  } else if (mode == 1) {
    // plain bf16 into Cb
#pragma unroll
    for (int mi = 0; mi < 8; ++mi) {
      int rbase = m0 + wr * 128 + mi * 16 + quad * 4;
#pragma unroll
      for (int nj = 0; nj < 4; ++nj) {
        int col = n0 - nsplit + wc * 64 + nj * 16 + l16;
        for (int r = 0; r < 4; ++r)
          Cb[(size_t)(rbase + r) * sb + col] = f2bf(acc[mi][nj][r]);
      }
    }
  } else {
    // V^T scatter: Cb is (B,H,128,S); 4 tokens contiguous per lane -> ushort4
#pragma unroll
    for (int mi = 0; mi < 8; ++mi) {
      int token0 = m0 + wr * 128 + mi * 16 + quad * 4;  // same b for r=0..3
#pragma unroll
      for (int nj = 0; nj < 4; ++nj) {
        int ch = n0 - nsplit + wc * 64 + nj * 16 + l16;  // h*128 + d
        size_t base = (((size_t)((token0 >> 11) * 16 + (ch >> 7)) * 128 + (ch & 127)) << 11) +
                      (token0 & 2047);
        ushort4 pk;
        pk.x = f2bf(acc[mi][nj][0]);
        pk.y = f2bf(acc[mi][nj][1]);
        pk.z = f2bf(acc[mi][nj][2]);
        pk.w = f2bf(acc[mi][nj][3]);
        *(ushort4*)(Cb + base) = pk;
      }
    }
  }
#undef ASLOT
#undef BSLOT
#undef STAGE_A
#undef STAGE_B
#undef FRAG
#undef SYNC_MID
}

// ---------------- RMSNorm over rows of 512, in place (bf16) ---------------------------
__global__ __launch_bounds__(256) void rmsnorm_kernel(u16* __restrict__ t,
                                                      const u16* __restrict__ w) {
  int row = blockIdx.x * 4 + (threadIdx.x >> 6);
  int lane = threadIdx.x & 63;
  u16* xr = t + (size_t)row * 512;
  float v[8];
  float ss = 0.f;
  for (int i = 0; i < 8; ++i) {
    v[i] = bf2f(xr[lane + i * 64]);
    ss += v[i] * v[i];
  }
  for (int d = 32; d > 0; d >>= 1) ss += __shfl_xor(ss, d);
  float r = rsqrtf(ss * (1.f / 512.f) + 1e-6f);
  for (int i = 0; i < 8; ++i) xr[lane + i * 64] = f2bf(v[i] * r * bf2f(w[lane + i * 64]));
}

// ---------------- Flash attention (causal), bf16 MFMA, log2-domain softmax ------------
// q PRE-SCALED by (1/sqrt(128))*log2e in gemm8 => scores are log2-domain; exp via
// raw v_exp_f32 (2^x). k: (B,S,H*128). vt: (B,H,128,S). o: (B,S,H*128).
// Row sums via ones-column MFMA; deferred-max (THR=8 log2).
__global__ __launch_bounds__(256) void attn_kernel(const u16* __restrict__ q,
                                                   const u16* __restrict__ k,
                                                   const u16* __restrict__ vt,
                                                   u16* __restrict__ o) {
  const int S = 2048;
  __shared__ __align__(16) u16 Kt[64 * 128];   // [key][chunk8 ^ (key&15)]
  __shared__ __align__(16) u16 Vt[128 * 64];   // [d][granule8 ^ (d&7)]
  __shared__ __align__(16) u16 P[4][16][64];   // [row][granule8 ^ (row&7)]
  const int t = threadIdx.x;
  const int w = t >> 6, lane = t & 63;
  const int quad = lane >> 4, l16 = lane & 15;
  const int bh = blockIdx.x;
  const int b = bh >> 4, h = bh & 15;
  const int qb = (int)gridDim.y - 1 - (int)blockIdx.y;  // heaviest first
  const int q0 = qb * 64 + w * 16;

  const u16* qbase = q + ((size_t)(b * S + q0 + l16)) * 2048 + h * 128;
  bf16x8 qf[4];
  for (int c = 0; c < 4; ++c) qf[c] = *(const bf16x8*)(qbase + c * 32 + quad * 8);

  const u16* kbase = k + (size_t)b * S * 2048 + h * 128;
  const u16* vtb = vt + (size_t)bh * 128 * S;

  const int ksrow = t >> 4, ksc = t & 15;  // K staging decode
  const int vsrow = t >> 3, vsc = t & 7;   // V staging decode

  bf16x8 onesf;  // B-operand of the row-sum MFMA: all 1.0 bf16
#pragma unroll
  for (int i = 0; i < 8; ++i) onesf[i] = (short)0x3F80;

  float m_i[4], l_i[4];
  floatx4 acc[8];
  for (int r = 0; r < 4; ++r) { m_i[r] = -1e30f; l_i[r] = 0.f; }
  for (int nd = 0; nd < 8; ++nd) acc[nd] = (floatx4){0.f, 0.f, 0.f, 0.f};

  const int kmax = q0 + 15;
  const int qbase64 = qb * 64;
  for (int kb = 0; kb <= qbase64; kb += 64) {
    const bool diag = (kb == qbase64);
    __syncthreads();
    for (int j = 0; j < 4; ++j) {
      int row = j * 16 + ksrow;
      GLOAD_LDS16(kbase + (size_t)(kb + row) * 2048 + (ksc ^ (row & 15)) * 8,
                  Kt + (size_t)(row * 16 + ksc) * 8);
    }
    for (int j = 0; j < 4; ++j) {
      int row = j * 32 + vsrow;
      GLOAD_LDS16(vtb + (size_t)row * S + kb + ((vsc ^ (row & 7)) * 8),
                  Vt + (size_t)(row * 8 + vsc) * 8);
    }
    __syncthreads();

    floatx4 s[4];
    if (!diag) {
      for (int ns = 0; ns < 4; ++ns) {
        s[ns] = (floatx4){0.f, 0.f, 0.f, 0.f};
        for (int c = 0; c < 4; ++c) {
          bf16x8 kf = *(const bf16x8*)&Kt[(ns * 16 + l16) * 128 + ((c * 4 + quad) ^ l16) * 8];
          s[ns] = __builtin_amdgcn_mfma_f32_16x16x32_bf16(qf[c], kf, s[ns], 0, 0, 0);
        }
      }
    } else {
      for (int ns = 0; ns < 4; ++ns) {
        if (kb + ns * 16 <= kmax) {
          s[ns] = (floatx4){0.f, 0.f, 0.f, 0.f};
          for (int c = 0; c < 4; ++c) {
            bf16x8 kf = *(const bf16x8*)&Kt[(ns * 16 + l16) * 128 + ((c * 4 + quad) ^ l16) * 8];
            s[ns] = __builtin_amdgcn_mfma_f32_16x16x32_bf16(qf[c], kf, s[ns], 0, 0, 0);
          }
          int key = kb + ns * 16 + l16;
          for (int r = 0; r < 4; ++r)
            s[ns][r] = (key > q0 + quad * 4 + r) ? -1e30f : s[ns][r];
        } else {
          s[ns] = (floatx4){-1e30f, -1e30f, -1e30f, -1e30f};
        }
      }
    }
    float tmax[4];
    for (int r = 0; r < 4; ++r) {
      float v = fmaxf(fmaxf(s[0][r], s[1][r]), fmaxf(s[2][r], s[3][r]));
      for (int d = 1; d < 16; d <<= 1) v = fmaxf(v, __shfl_xor(v, d));
      tmax[r] = v;
    }
    bool grow = (tmax[0] > m_i[0] + 8.f) || (tmax[1] > m_i[1] + 8.f) ||
                (tmax[2] > m_i[2] + 8.f) || (tmax[3] > m_i[3] + 8.f);
    if (__any(grow)) {
      for (int r = 0; r < 4; ++r) {
        float mn = fmaxf(m_i[r], tmax[r]);
        float alpha = exp2fast(m_i[r] - mn);
        m_i[r] = mn;
        l_i[r] *= alpha;
        for (int nd = 0; nd < 8; ++nd) acc[nd][r] *= alpha;
      }
    }
    for (int ns = 0; ns < 4; ++ns)
      for (int r = 0; r < 4; ++r) s[ns][r] = exp2fast(s[ns][r] - m_i[r]);
    for (int ns = 0; ns < 4; ++ns)
      for (int r = 0; r < 4; ++r) {
        int row = quad * 4 + r;
        P[w][row][(((ns * 2 + (l16 >> 3)) ^ (row & 7)) << 3) | (l16 & 7)] = f2bf_hu(s[ns][r]);
      }
    floatx4 ls = (floatx4){0.f, 0.f, 0.f, 0.f};
    for (int kc = 0; kc < 2; ++kc) {
      if (!diag || kb + kc * 32 <= kmax) {
        bf16x8 pa = *(const bf16x8*)&P[w][l16][((kc * 4 + quad) ^ (l16 & 7)) * 8];
        ls = __builtin_amdgcn_mfma_f32_16x16x32_bf16(pa, onesf, ls, 0, 0, 0);
        for (int nd = 0; nd < 8; ++nd) {
          int d = nd * 16 + l16;
          bf16x8 vf = *(const bf16x8*)&Vt[(d * 8 + ((kc * 4 + quad) ^ (d & 7))) * 8];
          acc[nd] = __builtin_amdgcn_mfma_f32_16x16x32_bf16(pa, vf, acc[nd], 0, 0, 0);
        }
      }
    }
    for (int r = 0; r < 4; ++r) l_i[r] += ls[r];
  }
  u16* ob = o + ((size_t)(b * S + q0 + quad * 4)) * 2048 + h * 128;
  for (int r = 0; r < 4; ++r) {
    float inv = 1.f / l_i[r];
    for (int nd = 0; nd < 8; ++nd)
      ob[(size_t)r * 2048 + nd * 16 + l16] = f2bf(acc[nd][r] * inv);
  }
}

// ------------------------------------ launcher ---------------------------------------
extern "C" void kernel_launch(void* const* d_in, const int* in_sizes, int n_in,
                              void* d_out, int out_size, void* d_ws, size_t ws_size,
                              hipStream_t stream) {
  const void* x    = d_in[0];  // (2,2048,2048)
  const void* fcos = d_in[1];  // (2048,64)
  const void* fsin = d_in[2];
  const void* wkv  = d_in[3];  // (2048,512)
  const void* wnr  = d_in[4];  // (512,)
  const void* wku  = d_in[5];  // (512,2048)
  const void* wvu  = d_in[6];  // (512,2048)
  const void* wq   = d_in[7];  // (2048,2048)
  const void* wo   = d_in[8];  // (2048,2048)
  const u16* probe = (const u16*)fcos;

  const size_t MB = 1u << 20;
  char* ws = (char*)d_ws;
  u16* xc    = (u16*)(ws);             // 16 MiB x bf16; dead after fused Q+KV
  u16* vtb   = (u16*)(ws);             //   ... then V^T (B,H,128,S), written by K+V gemm
  u16* qb    = (u16*)(ws + 16 * MB);   // 16 MiB q (rope'd, pre-scaled); dead after attn
  u16* kb    = (u16*)(ws + 32 * MB);   // 16 MiB k (rope'd)
  u16* ab    = (u16*)(ws + 48 * MB);   // 16 MiB attention output
  u16* lat   = (u16*)(ws + 64 * MB);   // 4 MiB kv latent
  u16* wqT   = (u16*)(ws + 68 * MB);   // 8 MiB; contiguous with wkvT -> fused B [2560,2048]
  u16* woT   = (u16*)(ws + 68 * MB);   //   ... then w_out^T (after Q+KV gemm)
  u16* wkvT  = (u16*)(ws + 76 * MB);   // 2 MiB
  u16* wkT   = (u16*)(ws + 78 * MB);   // 2 MiB; contiguous with wvT -> fused B [4096,512]
  u16* wvT   = (u16*)(ws + 80 * MB);   // 2 MiB
  u16* fcosc = (u16*)(ws + 82 * MB);   // 256 KiB
  u16* fsinc = (u16*)(ws + 82 * MB + 256 * 1024);
  u16* wnrc  = (u16*)(ws + 82 * MB + 512 * 1024);  // 1 KiB  (total < 83 MiB)

  // 1/sqrt(128) * log2(e): softmax runs in log2 domain (v_exp_f32 = 2^x)
  const float QSCALE = 0.08838834764831845f * 1.4426950408889634f;
  dim3 blk(256);

  // allow 128 KiB dynamic LDS for gemm8 (idempotent, non-stream API)
  hipFuncSetAttribute((const void*)gemm8, hipFuncAttributeMaxDynamicSharedMemorySize,
                      131072);

  // --- convert inputs to bf16 (identity copy if already bf16) ---
  cvt_to_bf16<<<dim3(4096), blk, 0, stream>>>(x, xc, 8388608, probe);
  cvt_to_bf16<<<dim3(64), blk, 0, stream>>>(fcos, fcosc, 131072, probe);
  cvt_to_bf16<<<dim3(64), blk, 0, stream>>>(fsin, fsinc, 131072, probe);
  cvt_to_bf16<<<dim3(1), blk, 0, stream>>>(wnr, wnrc, 512, probe);

  // --- weight transposes for the fused Q+KV gemm (B rows: wqT then wkvT, contiguous) --
  transpose_cvt<<<dim3(64, 64), blk, 0, stream>>>(wq, wqT, 2048, 2048, probe);
  transpose_cvt<<<dim3(16, 64), blk, 0, stream>>>(wkv, wkvT, 2048, 512, probe);

  // --- fused Q (rope, pre-scaled) + KV-compress: M=4096, N=2560, K=2048 ---
  gemm8<<<dim3(10, 16), dim3(512), 131072, stream>>>(xc, wqT, qb, 2048, lat, 512,
                                                     2560, 2048, 2048, 1,
                                                     fcosc, fsinc, QSCALE, probe);
  rmsnorm_kernel<<<dim3(1024), blk, 0, stream>>>(lat, wnrc);

  // --- fused K (rope) + V (direct V^T scatter): M=4096, N=4096, K=512 ---
  transpose_cvt<<<dim3(64, 16), blk, 0, stream>>>(wku, wkT, 512, 2048, probe);
  transpose_cvt<<<dim3(64, 16), blk, 0, stream>>>(wvu, wvT, 512, 2048, probe);
  gemm8<<<dim3(16, 16), dim3(512), 131072, stream>>>(lat, wkT, kb, 2048, vtb, 0,
                                                     4096, 512, 2048, 2,
                                                     fcosc, fsinc, 1.0f, probe);

  // --- w_out^T into dead wqT slot ---
  transpose_cvt<<<dim3(64, 64), blk, 0, stream>>>(wo, woT, 2048, 2048, probe);

  // --- causal flash attention (2D grid, heaviest qb dispatched first) ---
  attn_kernel<<<dim3(32, 32), blk, 0, stream>>>(qb, kb, vtb, ab);

  // --- output projection straight into d_out: M=4096, N=2048, K=2048 ---
  gemm8<<<dim3(8, 16), dim3(512), 131072, stream>>>(ab, woT, d_out, 2048, nullptr, 0,
                                                    2048, 2048, 0, 0,
                                                    nullptr, nullptr, 1.0f, probe);
}

// Round 4
// 386.912 us; speedup vs baseline: 1.1546x; 1.0062x over previous
//
#include <hip/hip_runtime.h>

typedef unsigned short u16;
typedef __attribute__((ext_vector_type(8))) short bf16x8;   // 8 bf16 = 4 VGPRs (MFMA A/B frag)
typedef __attribute__((ext_vector_type(4))) float floatx4;  // MFMA C/D frag

__device__ __forceinline__ float bf2f(u16 h) {
  return __uint_as_float(((unsigned int)h) << 16);
}
__device__ __forceinline__ u16 f2bf(float f) {
  unsigned int u = __float_as_uint(f);
  u += 0x7fffu + ((u >> 16) & 1u);  // RNE
  return (u16)(u >> 16);
}
// cheaper round-half-up (same 0.5 ulp bound) for the attention P pack
__device__ __forceinline__ u16 f2bf_hu(float f) {
  return (u16)((__float_as_uint(f) + 0x8000u) >> 16);
}
// raw v_exp_f32: computes 2^x (softmax runs in log2 domain; log2e folded into Q scale)
__device__ __forceinline__ float exp2fast(float x) {
  float r;
  asm("v_exp_f32 %0, %1" : "=v"(r) : "v"(x));
  return r;
}
// probe[0] is freqs_cos[0] == 1.0f: fp32 low u16 = 0x0000, bf16 = 0x3F80.
__device__ __forceinline__ bool is_f32(const u16* probe) { return probe[0] == 0; }

// async global->LDS, 16B per lane. LDS dest must be wave-uniform base + lane*16.
#define GLOAD_LDS16(gsrc, ldst)                                                        \
  __builtin_amdgcn_global_load_lds(                                                    \
      (const __attribute__((address_space(1))) unsigned int*)(gsrc),                   \
      (__attribute__((address_space(3))) unsigned int*)(ldst), 16, 0, 0)

// ------------- convert any input buffer (fp32 or bf16 per probe) -> bf16 --------------
__global__ __launch_bounds__(256) void cvt_to_bf16(const void* __restrict__ in,
                                                   u16* __restrict__ out, int n,
                                                   const u16* __restrict__ probe) {
  int i = (blockIdx.x * 256 + threadIdx.x) * 8;
  if (i >= n) return;
  if (is_f32(probe)) {
    const float* f = (const float*)in;
    uint4 o;
    o.x = (unsigned)f2bf(f[i + 0]) | ((unsigned)f2bf(f[i + 1]) << 16);
    o.y = (unsigned)f2bf(f[i + 2]) | ((unsigned)f2bf(f[i + 3]) << 16);
    o.z = (unsigned)f2bf(f[i + 4]) | ((unsigned)f2bf(f[i + 5]) << 16);
    o.w = (unsigned)f2bf(f[i + 6]) | ((unsigned)f2bf(f[i + 7]) << 16);
    *(uint4*)(out + i) = o;
  } else {
    *(uint4*)(out + i) = *(const uint4*)((const u16*)in + i);
  }
}

// ---------- transpose+convert: in (R,C) fp32/bf16 per probe -> out (C,R) bf16 ---------
__global__ __launch_bounds__(256) void transpose_cvt(const void* __restrict__ in,
                                                     u16* __restrict__ out,
                                                     int R, int C,
                                                     const u16* __restrict__ probe) {
  __shared__ u16 tile[32][33];
  int bx = blockIdx.x * 32;  // input col base
  int by = blockIdx.y * 32;  // input row base
  int tx = threadIdx.x & 31, ty = threadIdx.x >> 5;  // 32 x 8
  if (is_f32(probe)) {
    const float* f = (const float*)in;
    for (int i = 0; i < 32; i += 8)
      tile[ty + i][tx] = f2bf(f[(size_t)(by + ty + i) * C + (bx + tx)]);
  } else {
    const u16* u = (const u16*)in;
    for (int i = 0; i < 32; i += 8)
      tile[ty + i][tx] = u[(size_t)(by + ty + i) * C + (bx + tx)];
  }
  __syncthreads();
  for (int i = 0; i < 32; i += 8)
    out[(size_t)(bx + ty + i) * R + (by + tx)] = tile[tx][ty + i];
}

// ============ 256x128 8-wave deep-pipelined GEMM (grid-fill-fixed 8-phase port) =======
// C = A[M,K] * BT[N,K]^T.  BK=64 in two 32-halves; 2 phases per K-tile, 16 MFMA each.
// 8 waves in a 4x2 grid; each wave owns a 64x64 output block (acc[4][4], 64 VGPR).
// Phase: {8x ds_read_b128 frags; stage 3x global_load_lds (A-half 2 + B-half 1);
//         barrier; lgkmcnt(0); setprio(1); 16 MFMA; setprio(0); barrier}.
// Stage targets (tile u, cur=u&1, oth=cur^1):
//   ph1 -> (u+1) k1 into (oth,1) slots   [last read: tile u-1 ph2, barrier-closed]
//   ph2 -> (u+2) k0 into (cur,0) slots   [last read: this tile ph1, barrier-closed]
// Tile-end vmcnt(3): retires all but ph2's 3 issues -> (u+1)'s k0+k1 landed before
// tile u+1 reads them. Prologue stages t0k0,t0k1,t1k0 (9 issues), vmcnt(3).
// Granule XOR swizzle g ^= (r&3)^((r>>2)&3) on stage-source and ds_read (involution).
// LDS = 96 KiB (A: 4 x 16 KiB, B: 4 x 8 KiB) -> 1 block/CU.
// mode 0: plain into Ca (fp32 if probe fp32), stride sa.
// mode 1: cols [0,nsplit) RoPE*oscale -> Ca; cols [nsplit,N) plain bf16 -> Cb.
// mode 2: cols [0,nsplit) RoPE*oscale -> Ca; cols [nsplit,N) V^T scatter -> Cb (B,H,128,S).
__global__ __launch_bounds__(512, 2) void gemm28(const u16* __restrict__ A,
                                                 const u16* __restrict__ BT,
                                                 void* __restrict__ Ca, int sa,
                                                 u16* __restrict__ Cb, int sb,
                                                 int N, int K, int nsplit, int mode,
                                                 const u16* __restrict__ fc,
                                                 const u16* __restrict__ fs,
                                                 float oscale,
                                                 const u16* __restrict__ probe) {
  extern __shared__ __align__(16) u16 ldsbuf[];   // 98304 B
  u16* const AsB = ldsbuf;                        // 4 slots x 8192 u16 (256x32)
  u16* const BsB = ldsbuf + 32768;                // 4 slots x 4096 u16 (128x32)
#define ASLOT(b, k) (AsB + ((((b) << 1) | (k)) << 13))
#define BSLOT(b, k) (BsB + ((((b) << 1) | (k)) << 12))

  const int t = threadIdx.x;
  const int lane = t & 63, wid = t >> 6;
  const int quad = lane >> 4, l16 = lane & 15;
  const int wr = wid >> 1, wc = wid & 1;          // 4 x 2 wave grid; wave owns 64x64
  const int m0 = blockIdx.y * 256, n0 = blockIdx.x * 128;
  const int NT = K >> 6;                          // K >= 512 in all our calls

  const u16* const Abase = A + (size_t)m0 * K;
  const u16* const Bbase = BT + (size_t)n0 * K;

  // staging decode: A-half = 16 KiB = 2 issues (e0,e1); B-half = 8 KiB = 1 issue
  const int e0 = t, e1 = 512 + t;
  const int ra0 = e0 >> 2, ra1 = e1 >> 2;         // A rows 0..255
  const int sg0 = (e0 & 3) ^ ((ra0 & 3) ^ ((ra0 >> 2) & 3));
  const int sg1 = (e1 & 3) ^ ((ra1 & 3) ^ ((ra1 >> 2) & 3));
  const u16* const sa0 = Abase + (size_t)ra0 * K + sg0 * 8;
  const u16* const sa1 = Abase + (size_t)ra1 * K + sg1 * 8;
  const u16* const sb0 = Bbase + (size_t)ra0 * K + sg0 * 8;  // B rows 0..127 (=ra0)
#define STAGE_A(slot, kb)                      \
  do {                                         \
    GLOAD_LDS16(sa0 + (kb), (slot) + e0 * 8);  \
    GLOAD_LDS16(sa1 + (kb), (slot) + e1 * 8);  \
  } while (0)
#define STAGE_B(slot, kb) GLOAD_LDS16(sb0 + (kb), (slot) + e0 * 8)

  // frag read: row-base multiples of 16 contribute 0 to the swizzle
  const int gofs = (quad ^ ((l16 & 3) ^ ((l16 >> 2) & 3))) * 8;
#define FRAG(slot, row) (*(const bf16x8*)((slot) + (row) * 32 + gofs))

#define SYNC_MID()                                          \
  __builtin_amdgcn_s_barrier();                             \
  asm volatile("s_waitcnt lgkmcnt(0)" ::: "memory");        \
  __builtin_amdgcn_sched_barrier(0)

  floatx4 acc[4][4];
#pragma unroll
  for (int i = 0; i < 4; ++i)
#pragma unroll
    for (int j = 0; j < 4; ++j) acc[i][j] = (floatx4){0.f, 0.f, 0.f, 0.f};

  // ---- prologue: tile0 k0,k1 -> buf0; tile1 k0 -> buf1 (9 issues) ----
  STAGE_A(ASLOT(0, 0), 0);
  STAGE_B(BSLOT(0, 0), 0);
  STAGE_A(ASLOT(0, 1), 32);
  STAGE_B(BSLOT(0, 1), 32);
  STAGE_A(ASLOT(1, 0), 64);
  STAGE_B(BSLOT(1, 0), 64);
  asm volatile("s_waitcnt vmcnt(3)" ::: "memory");  // tile0 fully landed
  __builtin_amdgcn_s_barrier();

  bf16x8 af[4], bfr[4];
  const int arow = wr * 64 + l16;   // + mi*16
  const int brow = wc * 64 + l16;   // + nj*16

#pragma unroll 1
  for (int u = 0; u < NT; ++u) {
    const int cur = u & 1, oth = cur ^ 1;
    const bool s1 = (u + 1 < NT), s2 = (u + 2 < NT);
    const int kb1 = (u + 1) << 6, kb2 = (u + 2) << 6;

    // ---------------- phase 1: k-half 0 ----------------
#pragma unroll
    for (int mi = 0; mi < 4; ++mi) af[mi] = FRAG(ASLOT(cur, 0), arow + mi * 16);
#pragma unroll
    for (int nj = 0; nj < 4; ++nj) bfr[nj] = FRAG(BSLOT(cur, 0), brow + nj * 16);
    if (s1) {
      STAGE_A(ASLOT(oth, 1), kb1 + 32);
      STAGE_B(BSLOT(oth, 1), kb1 + 32);
    }
    SYNC_MID();
    __builtin_amdgcn_s_setprio(1);
#pragma unroll
    for (int mi = 0; mi < 4; ++mi)
#pragma unroll
      for (int nj = 0; nj < 4; ++nj)
        acc[mi][nj] = __builtin_amdgcn_mfma_f32_16x16x32_bf16(af[mi], bfr[nj], acc[mi][nj], 0, 0, 0);
    __builtin_amdgcn_s_setprio(0);
    __builtin_amdgcn_sched_barrier(0);
    __builtin_amdgcn_s_barrier();

    // ---------------- phase 2: k-half 1 ----------------
#pragma unroll
    for (int mi = 0; mi < 4; ++mi) af[mi] = FRAG(ASLOT(cur, 1), arow + mi * 16);
#pragma unroll
    for (int nj = 0; nj < 4; ++nj) bfr[nj] = FRAG(BSLOT(cur, 1), brow + nj * 16);
    if (s2) {
      STAGE_A(ASLOT(cur, 0), kb2);
      STAGE_B(BSLOT(cur, 0), kb2);
    }
    SYNC_MID();
    __builtin_amdgcn_s_setprio(1);
#pragma unroll
    for (int mi = 0; mi < 4; ++mi)
#pragma unroll
      for (int nj = 0; nj < 4; ++nj)
        acc[mi][nj] = __builtin_amdgcn_mfma_f32_16x16x32_bf16(af[mi], bfr[nj], acc[mi][nj], 0, 0, 0);
    __builtin_amdgcn_s_setprio(0);
    __builtin_amdgcn_sched_barrier(0);
    if (s2)
      asm volatile("s_waitcnt vmcnt(3)" ::: "memory");  // retire thru (u+1)'s k1
    else
      asm volatile("s_waitcnt vmcnt(0)" ::: "memory");  // tail drain
    __builtin_amdgcn_s_barrier();
  }

  // ---------------- epilogue ----------------
  if (mode == 0) {
    const bool f32o = is_f32(probe);
#pragma unroll
    for (int mi = 0; mi < 4; ++mi) {
      int rbase = m0 + wr * 64 + mi * 16 + quad * 4;
#pragma unroll
      for (int nj = 0; nj < 4; ++nj) {
        int col = n0 + wc * 64 + nj * 16 + l16;
        if (f32o) {
          float* Cf = (float*)Ca;
          for (int r = 0; r < 4; ++r) Cf[(size_t)(rbase + r) * sa + col] = acc[mi][nj][r];
        } else {
          u16* Ch = (u16*)Ca;
          for (int r = 0; r < 4; ++r) Ch[(size_t)(rbase + r) * sa + col] = f2bf(acc[mi][nj][r]);
        }
      }
    }
  } else if (n0 < nsplit) {
    // RoPE epilogue: col pairs live in adjacent lanes (head dim 128)
    const bool odd = (l16 & 1);
    u16* Ch = (u16*)Ca;
#pragma unroll
    for (int mi = 0; mi < 4; ++mi) {
      int rbase = m0 + wr * 64 + mi * 16 + quad * 4;
#pragma unroll
      for (int nj = 0; nj < 4; ++nj) {
        int col = n0 + wc * 64 + nj * 16 + l16;
        int p = (col & 127) >> 1;  // pair index within head (0..63)
        for (int r = 0; r < 4; ++r) {
          int srow = (rbase + r) & 2047;  // token index (M = B*2048)
          float c = bf2f(fc[srow * 64 + p]);
          float sn = bf2f(fs[srow * 64 + p]);
          float v = acc[mi][nj][r];
          float pv = __shfl_xor(v, 1);
          float o = fmaf(v, c, odd ? pv * sn : -pv * sn);
          Ch[(size_t)(rbase + r) * sa + col] = f2bf(o * oscale);
        }
      }
    }
  } else if (mode == 1) {
    // plain bf16 into Cb
#pragma unroll
    for (int mi = 0; mi < 4; ++mi) {
      int rbase = m0 + wr * 64 + mi * 16 + quad * 4;
#pragma unroll
      for (int nj = 0; nj < 4; ++nj) {
        int col = n0 - nsplit + wc * 64 + nj * 16 + l16;
        for (int r = 0; r < 4; ++r)
          Cb[(size_t)(rbase + r) * sb + col] = f2bf(acc[mi][nj][r]);
      }
    }
  } else {
    // V^T scatter: Cb is (B,H,128,S); 4 tokens contiguous per lane -> ushort4
#pragma unroll
    for (int mi = 0; mi < 4; ++mi) {
      int token0 = m0 + wr * 64 + mi * 16 + quad * 4;  // same b for r=0..3
#pragma unroll
      for (int nj = 0; nj < 4; ++nj) {
        int ch = n0 - nsplit + wc * 64 + nj * 16 + l16;  // h*128 + d
        size_t base = (((size_t)((token0 >> 11) * 16 + (ch >> 7)) * 128 + (ch & 127)) << 11) +
                      (token0 & 2047);
        ushort4 pk;
        pk.x = f2bf(acc[mi][nj][0]);
        pk.y = f2bf(acc[mi][nj][1]);
        pk.z = f2bf(acc[mi][nj][2]);
        pk.w = f2bf(acc[mi][nj][3]);
        *(ushort4*)(Cb + base) = pk;
      }
    }
  }
#undef ASLOT
#undef BSLOT
#undef STAGE_A
#undef STAGE_B
#undef FRAG
#undef SYNC_MID
}

// ---------------- RMSNorm over rows of 512, in place (bf16) ---------------------------
__global__ __launch_bounds__(256) void rmsnorm_kernel(u16* __restrict__ t,
                                                      const u16* __restrict__ w) {
  int row = blockIdx.x * 4 + (threadIdx.x >> 6);
  int lane = threadIdx.x & 63;
  u16* xr = t + (size_t)row * 512;
  float v[8];
  float ss = 0.f;
  for (int i = 0; i < 8; ++i) {
    v[i] = bf2f(xr[lane + i * 64]);
    ss += v[i] * v[i];
  }
  for (int d = 32; d > 0; d >>= 1) ss += __shfl_xor(ss, d);
  float r = rsqrtf(ss * (1.f / 512.f) + 1e-6f);
  for (int i = 0; i < 8; ++i) xr[lane + i * 64] = f2bf(v[i] * r * bf2f(w[lane + i * 64]));
}

// ---------------- Flash attention (causal), bf16 MFMA, log2-domain softmax ------------
// q PRE-SCALED by (1/sqrt(128))*log2e => scores are log2-domain; exp via v_exp_f32.
// k: (B,S,H*128). vt: (B,H,128,S). o: (B,S,H*128).
// Row sums via ones-column MFMA; deferred-max (THR=8 log2).
__global__ __launch_bounds__(256) void attn_kernel(const u16* __restrict__ q,
                                                   const u16* __restrict__ k,
                                                   const u16* __restrict__ vt,
                                                   u16* __restrict__ o) {
  const int S = 2048;
  __shared__ __align__(16) u16 Kt[64 * 128];   // [key][chunk8 ^ (key&15)]
  __shared__ __align__(16) u16 Vt[128 * 64];   // [d][granule8 ^ (d&7)]
  __shared__ __align__(16) u16 P[4][16][64];   // [row][granule8 ^ (row&7)]
  const int t = threadIdx.x;
  const int w = t >> 6, lane = t & 63;
  const int quad = lane >> 4, l16 = lane & 15;
  const int bh = blockIdx.x;
  const int b = bh >> 4, h = bh & 15;
  const int qb = (int)gridDim.y - 1 - (int)blockIdx.y;  // heaviest first
  const int q0 = qb * 64 + w * 16;

  const u16* qbase = q + ((size_t)(b * S + q0 + l16)) * 2048 + h * 128;
  bf16x8 qf[4];
  for (int c = 0; c < 4; ++c) qf[c] = *(const bf16x8*)(qbase + c * 32 + quad * 8);

  const u16* kbase = k + (size_t)b * S * 2048 + h * 128;
  const u16* vtb = vt + (size_t)bh * 128 * S;

  const int ksrow = t >> 4, ksc = t & 15;  // K staging decode
  const int vsrow = t >> 3, vsc = t & 7;   // V staging decode

  bf16x8 onesf;  // B-operand of the row-sum MFMA: all 1.0 bf16
#pragma unroll
  for (int i = 0; i < 8; ++i) onesf[i] = (short)0x3F80;

  float m_i[4], l_i[4];
  floatx4 acc[8];
  for (int r = 0; r < 4; ++r) { m_i[r] = -1e30f; l_i[r] = 0.f; }
  for (int nd = 0; nd < 8; ++nd) acc[nd] = (floatx4){0.f, 0.f, 0.f, 0.f};

  const int kmax = q0 + 15;
  const int qbase64 = qb * 64;
  for (int kb = 0; kb <= qbase64; kb += 64) {
    const bool diag = (kb == qbase64);
    __syncthreads();
    for (int j = 0; j < 4; ++j) {
      int row = j * 16 + ksrow;
      GLOAD_LDS16(kbase + (size_t)(kb + row) * 2048 + (ksc ^ (row & 15)) * 8,
                  Kt + (size_t)(row * 16 + ksc) * 8);
    }
    for (int j = 0; j < 4; ++j) {
      int row = j * 32 + vsrow;
      GLOAD_LDS16(vtb + (size_t)row * S + kb + ((vsc ^ (row & 7)) * 8),
                  Vt + (size_t)(row * 8 + vsc) * 8);
    }
    __syncthreads();

    floatx4 s[4];
    if (!diag) {
      for (int ns = 0; ns < 4; ++ns) {
        s[ns] = (floatx4){0.f, 0.f, 0.f, 0.f};
        for (int c = 0; c < 4; ++c) {
          bf16x8 kf = *(const bf16x8*)&Kt[(ns * 16 + l16) * 128 + ((c * 4 + quad) ^ l16) * 8];
          s[ns] = __builtin_amdgcn_mfma_f32_16x16x32_bf16(qf[c], kf, s[ns], 0, 0, 0);
        }
      }
    } else {
      for (int ns = 0; ns < 4; ++ns) {
        if (kb + ns * 16 <= kmax) {
          s[ns] = (floatx4){0.f, 0.f, 0.f, 0.f};
          for (int c = 0; c < 4; ++c) {
            bf16x8 kf = *(const bf16x8*)&Kt[(ns * 16 + l16) * 128 + ((c * 4 + quad) ^ l16) * 8];
            s[ns] = __builtin_amdgcn_mfma_f32_16x16x32_bf16(qf[c], kf, s[ns], 0, 0, 0);
          }
          int key = kb + ns * 16 + l16;
          for (int r = 0; r < 4; ++r)
            s[ns][r] = (key > q0 + quad * 4 + r) ? -1e30f : s[ns][r];
        } else {
          s[ns] = (floatx4){-1e30f, -1e30f, -1e30f, -1e30f};
        }
      }
    }
    float tmax[4];
    for (int r = 0; r < 4; ++r) {
      float v = fmaxf(fmaxf(s[0][r], s[1][r]), fmaxf(s[2][r], s[3][r]));
      for (int d = 1; d < 16; d <<= 1) v = fmaxf(v, __shfl_xor(v, d));
      tmax[r] = v;
    }
    bool grow = (tmax[0] > m_i[0] + 8.f) || (tmax[1] > m_i[1] + 8.f) ||
                (tmax[2] > m_i[2] + 8.f) || (tmax[3] > m_i[3] + 8.f);
    if (__any(grow)) {
      for (int r = 0; r < 4; ++r) {
        float mn = fmaxf(m_i[r], tmax[r]);
        float alpha = exp2fast(m_i[r] - mn);
        m_i[r] = mn;
        l_i[r] *= alpha;
        for (int nd = 0; nd < 8; ++nd) acc[nd][r] *= alpha;
      }
    }
    for (int ns = 0; ns < 4; ++ns)
      for (int r = 0; r < 4; ++r) s[ns][r] = exp2fast(s[ns][r] - m_i[r]);
    for (int ns = 0; ns < 4; ++ns)
      for (int r = 0; r < 4; ++r) {
        int row = quad * 4 + r;
        P[w][row][(((ns * 2 + (l16 >> 3)) ^ (row & 7)) << 3) | (l16 & 7)] = f2bf_hu(s[ns][r]);
      }
    floatx4 ls = (floatx4){0.f, 0.f, 0.f, 0.f};
    for (int kc = 0; kc < 2; ++kc) {
      if (!diag || kb + kc * 32 <= kmax) {
        bf16x8 pa = *(const bf16x8*)&P[w][l16][((kc * 4 + quad) ^ (l16 & 7)) * 8];
        ls = __builtin_amdgcn_mfma_f32_16x16x32_bf16(pa, onesf, ls, 0, 0, 0);
        for (int nd = 0; nd < 8; ++nd) {
          int d = nd * 16 + l16;
          bf16x8 vf = *(const bf16x8*)&Vt[(d * 8 + ((kc * 4 + quad) ^ (d & 7))) * 8];
          acc[nd] = __builtin_amdgcn_mfma_f32_16x16x32_bf16(pa, vf, acc[nd], 0, 0, 0);
        }
      }
    }
    for (int r = 0; r < 4; ++r) l_i[r] += ls[r];
  }
  u16* ob = o + ((size_t)(b * S + q0 + quad * 4)) * 2048 + h * 128;
  for (int r = 0; r < 4; ++r) {
    float inv = 1.f / l_i[r];
    for (int nd = 0; nd < 8; ++nd)
      ob[(size_t)r * 2048 + nd * 16 + l16] = f2bf(acc[nd][r] * inv);
  }
}

// ------------------------------------ launcher ---------------------------------------
extern "C" void kernel_launch(void* const* d_in, const int* in_sizes, int n_in,
                              void* d_out, int out_size, void* d_ws, size_t ws_size,
                              hipStream_t stream) {
  const void* x    = d_in[0];  // (2,2048,2048)
  const void* fcos = d_in[1];  // (2048,64)
  const void* fsin = d_in[2];
  const void* wkv  = d_in[3];  // (2048,512)
  const void* wnr  = d_in[4];  // (512,)
  const void* wku  = d_in[5];  // (512,2048)
  const void* wvu  = d_in[6];  // (512,2048)
  const void* wq   = d_in[7];  // (2048,2048)
  const void* wo   = d_in[8];  // (2048,2048)
  const u16* probe = (const u16*)fcos;

  const size_t MB = 1u << 20;
  char* ws = (char*)d_ws;
  u16* xc    = (u16*)(ws);             // 16 MiB x bf16; dead after fused Q+KV
  u16* vtb   = (u16*)(ws);             //   ... then V^T (B,H,128,S), written by K+V gemm
  u16* qb    = (u16*)(ws + 16 * MB);   // 16 MiB q (rope'd, pre-scaled); dead after attn
  u16* kb    = (u16*)(ws + 32 * MB);   // 16 MiB k (rope'd)
  u16* ab    = (u16*)(ws + 48 * MB);   // 16 MiB attention output
  u16* lat   = (u16*)(ws + 64 * MB);   // 4 MiB kv latent
  u16* wqT   = (u16*)(ws + 68 * MB);   // 8 MiB; contiguous with wkvT -> fused B [2560,2048]
  u16* woT   = (u16*)(ws + 68 * MB);   //   ... then w_out^T (after Q+KV gemm)
  u16* wkvT  = (u16*)(ws + 76 * MB);   // 2 MiB
  u16* wkT   = (u16*)(ws + 78 * MB);   // 2 MiB; contiguous with wvT -> fused B [4096,512]
  u16* wvT   = (u16*)(ws + 80 * MB);   // 2 MiB
  u16* fcosc = (u16*)(ws + 82 * MB);   // 256 KiB
  u16* fsinc = (u16*)(ws + 82 * MB + 256 * 1024);
  u16* wnrc  = (u16*)(ws + 82 * MB + 512 * 1024);  // 1 KiB  (total < 83 MiB)

  // 1/sqrt(128) * log2(e): softmax runs in log2 domain (v_exp_f32 = 2^x)
  const float QSCALE = 0.08838834764831845f * 1.4426950408889634f;
  dim3 blk(256);

  // allow 96 KiB dynamic LDS for gemm28 (idempotent, non-stream API)
  hipFuncSetAttribute((const void*)gemm28, hipFuncAttributeMaxDynamicSharedMemorySize,
                      98304);

  // --- convert inputs to bf16 (identity copy if already bf16) ---
  cvt_to_bf16<<<dim3(4096), blk, 0, stream>>>(x, xc, 8388608, probe);
  cvt_to_bf16<<<dim3(64), blk, 0, stream>>>(fcos, fcosc, 131072, probe);
  cvt_to_bf16<<<dim3(64), blk, 0, stream>>>(fsin, fsinc, 131072, probe);
  cvt_to_bf16<<<dim3(1), blk, 0, stream>>>(wnr, wnrc, 512, probe);

  // --- weight transposes for the fused Q+KV gemm (B rows: wqT then wkvT, contiguous) --
  transpose_cvt<<<dim3(64, 64), blk, 0, stream>>>(wq, wqT, 2048, 2048, probe);
  transpose_cvt<<<dim3(16, 64), blk, 0, stream>>>(wkv, wkvT, 2048, 512, probe);

  // --- fused Q (rope, pre-scaled) + KV-compress: M=4096, N=2560, K=2048 (320 blocks) --
  gemm28<<<dim3(20, 16), dim3(512), 98304, stream>>>(xc, wqT, qb, 2048, lat, 512,
                                                     2560, 2048, 2048, 1,
                                                     fcosc, fsinc, QSCALE, probe);
  rmsnorm_kernel<<<dim3(1024), blk, 0, stream>>>(lat, wnrc);

  // --- fused K (rope) + V (direct V^T scatter): M=4096, N=4096, K=512 (512 blocks) ----
  transpose_cvt<<<dim3(64, 16), blk, 0, stream>>>(wku, wkT, 512, 2048, probe);
  transpose_cvt<<<dim3(64, 16), blk, 0, stream>>>(wvu, wvT, 512, 2048, probe);
  gemm28<<<dim3(32, 16), dim3(512), 98304, stream>>>(lat, wkT, kb, 2048, vtb, 0,
                                                     4096, 512, 2048, 2,
                                                     fcosc, fsinc, 1.0f, probe);

  // --- w_out^T into dead wqT slot ---
  transpose_cvt<<<dim3(64, 64), blk, 0, stream>>>(wo, woT, 2048, 2048, probe);

  // --- causal flash attention (2D grid, heaviest qb dispatched first) ---
  attn_kernel<<<dim3(32, 32), blk, 0, stream>>>(qb, kb, vtb, ab);

  // --- output projection straight into d_out: M=4096, N=2048, K=2048 (256 blocks) -----
  gemm28<<<dim3(16, 16), dim3(512), 98304, stream>>>(ab, woT, d_out, 2048, nullptr, 0,
                                                     2048, 2048, 0, 0,
                                                     nullptr, nullptr, 1.0f, probe);
}

// Round 5
// 371.862 us; speedup vs baseline: 1.2014x; 1.0405x over previous
//
#include <hip/hip_runtime.h>

typedef unsigned short u16;
typedef __attribute__((ext_vector_type(8))) short bf16x8;   // 8 bf16 = 4 VGPRs (MFMA A/B frag)
typedef __attribute__((ext_vector_type(4))) float floatx4;  // MFMA C/D frag

__device__ __forceinline__ float bf2f(u16 h) {
  return __uint_as_float(((unsigned int)h) << 16);
}
__device__ __forceinline__ u16 f2bf(float f) {
  unsigned int u = __float_as_uint(f);
  u += 0x7fffu + ((u >> 16) & 1u);  // RNE
  return (u16)(u >> 16);
}
// cheaper round-half-up (same 0.5 ulp bound) for the attention P pack
__device__ __forceinline__ u16 f2bf_hu(float f) {
  return (u16)((__float_as_uint(f) + 0x8000u) >> 16);
}
// raw v_exp_f32: computes 2^x (softmax runs in log2 domain; log2e folded into Q scale)
__device__ __forceinline__ float exp2fast(float x) {
  float r;
  asm("v_exp_f32 %0, %1" : "=v"(r) : "v"(x));
  return r;
}
// probe[0] is freqs_cos[0] == 1.0f: fp32 low u16 = 0x0000, bf16 = 0x3F80.
__device__ __forceinline__ bool is_f32(const u16* probe) { return probe[0] == 0; }

// async global->LDS, 16B per lane. LDS dest must be wave-uniform base + lane*16.
#define GLOAD_LDS16(gsrc, ldst)                                                        \
  __builtin_amdgcn_global_load_lds(                                                    \
      (const __attribute__((address_space(1))) unsigned int*)(gsrc),                   \
      (__attribute__((address_space(3))) unsigned int*)(ldst), 16, 0, 0)

// ------------- convert any input buffer (fp32 or bf16 per probe) -> bf16 --------------
__global__ __launch_bounds__(256) void cvt_to_bf16(const void* __restrict__ in,
                                                   u16* __restrict__ out, int n,
                                                   const u16* __restrict__ probe) {
  int i = (blockIdx.x * 256 + threadIdx.x) * 8;
  if (i >= n) return;
  if (is_f32(probe)) {
    const float* f = (const float*)in;
    uint4 o;
    o.x = (unsigned)f2bf(f[i + 0]) | ((unsigned)f2bf(f[i + 1]) << 16);
    o.y = (unsigned)f2bf(f[i + 2]) | ((unsigned)f2bf(f[i + 3]) << 16);
    o.z = (unsigned)f2bf(f[i + 4]) | ((unsigned)f2bf(f[i + 5]) << 16);
    o.w = (unsigned)f2bf(f[i + 6]) | ((unsigned)f2bf(f[i + 7]) << 16);
    *(uint4*)(out + i) = o;
  } else {
    *(uint4*)(out + i) = *(const uint4*)((const u16*)in + i);
  }
}

// ---------- transpose+convert: in (R,C) fp32/bf16 per probe -> out (C,R) bf16 ---------
__global__ __launch_bounds__(256) void transpose_cvt(const void* __restrict__ in,
                                                     u16* __restrict__ out,
                                                     int R, int C,
                                                     const u16* __restrict__ probe) {
  __shared__ u16 tile[32][33];
  int bx = blockIdx.x * 32;  // input col base
  int by = blockIdx.y * 32;  // input row base
  int tx = threadIdx.x & 31, ty = threadIdx.x >> 5;  // 32 x 8
  if (is_f32(probe)) {
    const float* f = (const float*)in;
    for (int i = 0; i < 32; i += 8)
      tile[ty + i][tx] = f2bf(f[(size_t)(by + ty + i) * C + (bx + tx)]);
  } else {
    const u16* u = (const u16*)in;
    for (int i = 0; i < 32; i += 8)
      tile[ty + i][tx] = u[(size_t)(by + ty + i) * C + (bx + tx)];
  }
  __syncthreads();
  for (int i = 0; i < 32; i += 8)
    out[(size_t)(bx + ty + i) * R + (by + tx)] = tile[tx][ty + i];
}

// ============ 128x128 8-wave pipelined GEMM, 64 KiB LDS -> 2 blocks/CU ================
// C = A[M,K] * BT[N,K]^T.  BK=64 in two 32-halves; 2 phases per K-tile, 8 MFMA each.
// 8 waves in a 2x4 grid; wave owns 64x32 (acc[4][2], 32 VGPR).
// Phase: {6x ds_read_b128 frags; stage 2x global_load_lds (A-half + B-half, 8 KiB ea);
//         barrier; lgkmcnt(0); setprio(1); 8 MFMA; setprio(0); barrier}.
// Stage targets (tile u, cur=u&1, oth=cur^1):
//   ph1 -> (u+1).k1 into (oth,1)   [last read: tile u-1 ph2, barrier-closed]
//   ph2 -> (u+2).k0 into (cur,0)   [last read: this tile ph1, barrier-closed]
// Tile-end vmcnt(2): keeps ph2's own 2 issues, retires (u+1).k0 and (u+1).k1.
// Prologue: t0k0,t0k1,t1k0 (6 issues), vmcnt(2). Tail: s2 false -> vmcnt(0).
// Granule XOR swizzle g ^= (r&3)^((r>>2)&3) on stage-source and ds_read (involution;
// conflict-free b128 reads). 2 blocks/CU (the m114 cross-block overlap mechanism) is
// the small-shape lever r3/r4's 1-block/CU 96-128 KiB variants denied.
// mode 0: plain into Ca (fp32 if probe fp32), stride sa.
// mode 1: cols [0,nsplit) RoPE*oscale -> Ca; cols [nsplit,N) plain bf16 -> Cb.
// mode 2: cols [0,nsplit) RoPE*oscale -> Ca; cols [nsplit,N) V^T scatter -> Cb (B,H,128,S).
__global__ __launch_bounds__(512, 4) void gemm128(const u16* __restrict__ A,
                                                  const u16* __restrict__ BT,
                                                  void* __restrict__ Ca, int sa,
                                                  u16* __restrict__ Cb, int sb,
                                                  int N, int K, int nsplit, int mode,
                                                  const u16* __restrict__ fc,
                                                  const u16* __restrict__ fs,
                                                  float oscale,
                                                  const u16* __restrict__ probe) {
  __shared__ __align__(16) u16 lds[32768];        // 64 KiB: A 2x2 slots, B 2x2 slots
  u16* const AsB = lds;                           // 4 slots x 4096 u16 (128 x 32)
  u16* const BsB = lds + 16384;
#define ASLOT(b, k) (AsB + ((((b) << 1) | (k)) << 12))
#define BSLOT(b, k) (BsB + ((((b) << 1) | (k)) << 12))

  const int t = threadIdx.x;
  const int lane = t & 63, wid = t >> 6;
  const int quad = lane >> 4, l16 = lane & 15;
  const int wr = wid >> 2, wc = wid & 3;          // 2 x 4 wave grid; wave owns 64x32
  const int m0 = blockIdx.y * 128, n0 = blockIdx.x * 128;
  const int NT = K >> 6;                          // K >= 512 in all our calls

  const u16* const Abase = A + (size_t)m0 * K;
  const u16* const Bbase = BT + (size_t)n0 * K;

  // staging decode: half-tile (128 rows x 32 k) = 8 KiB = 1 issue per thread
  const int rw = t >> 2;                          // row 0..127
  const int sg = (t & 3) ^ ((rw & 3) ^ ((rw >> 2) & 3));
  const u16* const sA = Abase + (size_t)rw * K + sg * 8;
  const u16* const sB = Bbase + (size_t)rw * K + sg * 8;
#define STAGE_A(slot, kb) GLOAD_LDS16(sA + (kb), (slot) + t * 8)
#define STAGE_B(slot, kb) GLOAD_LDS16(sB + (kb), (slot) + t * 8)

  // frag read: row base multiples of 16 contribute 0 to the swizzle
  const int gofs = (quad ^ ((l16 & 3) ^ ((l16 >> 2) & 3))) * 8;
#define FRAG(slot, row) (*(const bf16x8*)((slot) + (row) * 32 + gofs))

#define SYNC_MID()                                          \
  __builtin_amdgcn_s_barrier();                             \
  asm volatile("s_waitcnt lgkmcnt(0)" ::: "memory");        \
  __builtin_amdgcn_sched_barrier(0)

  floatx4 acc[4][2];
#pragma unroll
  for (int i = 0; i < 4; ++i)
#pragma unroll
    for (int j = 0; j < 2; ++j) acc[i][j] = (floatx4){0.f, 0.f, 0.f, 0.f};

  // ---- prologue: tile0 k0,k1 -> buf0; tile1 k0 -> buf1 (6 issues) ----
  STAGE_A(ASLOT(0, 0), 0);
  STAGE_B(BSLOT(0, 0), 0);
  STAGE_A(ASLOT(0, 1), 32);
  STAGE_B(BSLOT(0, 1), 32);
  STAGE_A(ASLOT(1, 0), 64);
  STAGE_B(BSLOT(1, 0), 64);
  asm volatile("s_waitcnt vmcnt(2)" ::: "memory");  // tile0 fully landed
  __builtin_amdgcn_s_barrier();

  bf16x8 af[4], bfr[2];
  const int arow = wr * 64 + l16;   // + mi*16
  const int brow = wc * 32 + l16;   // + nj*16

#pragma unroll 1
  for (int u = 0; u < NT; ++u) {
    const int cur = u & 1, oth = cur ^ 1;
    const bool s1 = (u + 1 < NT), s2 = (u + 2 < NT);
    const int kb1 = (u + 1) << 6, kb2 = (u + 2) << 6;

    // ---------------- phase 1: k-half 0 ----------------
#pragma unroll
    for (int mi = 0; mi < 4; ++mi) af[mi] = FRAG(ASLOT(cur, 0), arow + mi * 16);
#pragma unroll
    for (int nj = 0; nj < 2; ++nj) bfr[nj] = FRAG(BSLOT(cur, 0), brow + nj * 16);
    if (s1) {
      STAGE_A(ASLOT(oth, 1), kb1 + 32);
      STAGE_B(BSLOT(oth, 1), kb1 + 32);
    }
    SYNC_MID();
    __builtin_amdgcn_s_setprio(1);
#pragma unroll
    for (int mi = 0; mi < 4; ++mi)
#pragma unroll
      for (int nj = 0; nj < 2; ++nj)
        acc[mi][nj] = __builtin_amdgcn_mfma_f32_16x16x32_bf16(af[mi], bfr[nj], acc[mi][nj], 0, 0, 0);
    __builtin_amdgcn_s_setprio(0);
    __builtin_amdgcn_sched_barrier(0);
    __builtin_amdgcn_s_barrier();

    // ---------------- phase 2: k-half 1 ----------------
#pragma unroll
    for (int mi = 0; mi < 4; ++mi) af[mi] = FRAG(ASLOT(cur, 1), arow + mi * 16);
#pragma unroll
    for (int nj = 0; nj < 2; ++nj) bfr[nj] = FRAG(BSLOT(cur, 1), brow + nj * 16);
    if (s2) {
      STAGE_A(ASLOT(cur, 0), kb2);
      STAGE_B(BSLOT(cur, 0), kb2);
    }
    SYNC_MID();
    __builtin_amdgcn_s_setprio(1);
#pragma unroll
    for (int mi = 0; mi < 4; ++mi)
#pragma unroll
      for (int nj = 0; nj < 2; ++nj)
        acc[mi][nj] = __builtin_amdgcn_mfma_f32_16x16x32_bf16(af[mi], bfr[nj], acc[mi][nj], 0, 0, 0);
    __builtin_amdgcn_s_setprio(0);
    __builtin_amdgcn_sched_barrier(0);
    if (s2)
      asm volatile("s_waitcnt vmcnt(2)" ::: "memory");  // retire thru (u+1).k1
    else
      asm volatile("s_waitcnt vmcnt(0)" ::: "memory");  // tail drain
    __builtin_amdgcn_s_barrier();
  }

  // ---------------- epilogue ----------------
  if (mode == 0) {
    const bool f32o = is_f32(probe);
#pragma unroll
    for (int mi = 0; mi < 4; ++mi) {
      int rbase = m0 + wr * 64 + mi * 16 + quad * 4;
#pragma unroll
      for (int nj = 0; nj < 2; ++nj) {
        int col = n0 + wc * 32 + nj * 16 + l16;
        if (f32o) {
          float* Cf = (float*)Ca;
          for (int r = 0; r < 4; ++r) Cf[(size_t)(rbase + r) * sa + col] = acc[mi][nj][r];
        } else {
          u16* Ch = (u16*)Ca;
          for (int r = 0; r < 4; ++r) Ch[(size_t)(rbase + r) * sa + col] = f2bf(acc[mi][nj][r]);
        }
      }
    }
  } else if (n0 < nsplit) {
    // RoPE epilogue: col pairs live in adjacent lanes (head dim 128 aligns to tile)
    const bool odd = (l16 & 1);
    u16* Ch = (u16*)Ca;
#pragma unroll
    for (int mi = 0; mi < 4; ++mi) {
      int rbase = m0 + wr * 64 + mi * 16 + quad * 4;
#pragma unroll
      for (int nj = 0; nj < 2; ++nj) {
        int col = n0 + wc * 32 + nj * 16 + l16;
        int p = (col & 127) >> 1;  // pair index within head (0..63)
        for (int r = 0; r < 4; ++r) {
          int srow = (rbase + r) & 2047;  // token index (M = B*2048)
          float c = bf2f(fc[srow * 64 + p]);
          float sn = bf2f(fs[srow * 64 + p]);
          float v = acc[mi][nj][r];
          float pv = __shfl_xor(v, 1);
          float o = fmaf(v, c, odd ? pv * sn : -pv * sn);
          Ch[(size_t)(rbase + r) * sa + col] = f2bf(o * oscale);
        }
      }
    }
  } else if (mode == 1) {
    // plain bf16 into Cb
#pragma unroll
    for (int mi = 0; mi < 4; ++mi) {
      int rbase = m0 + wr * 64 + mi * 16 + quad * 4;
#pragma unroll
      for (int nj = 0; nj < 2; ++nj) {
        int col = n0 - nsplit + wc * 32 + nj * 16 + l16;
        for (int r = 0; r < 4; ++r)
          Cb[(size_t)(rbase + r) * sb + col] = f2bf(acc[mi][nj][r]);
      }
    }
  } else {
    // V^T scatter: Cb is (B,H,128,S); 4 tokens contiguous per lane -> ushort4
#pragma unroll
    for (int mi = 0; mi < 4; ++mi) {
      int token0 = m0 + wr * 64 + mi * 16 + quad * 4;  // same b for r=0..3
#pragma unroll
      for (int nj = 0; nj < 2; ++nj) {
        int ch = n0 - nsplit + wc * 32 + nj * 16 + l16;  // h*128 + d
        size_t base = (((size_t)((token0 >> 11) * 16 + (ch >> 7)) * 128 + (ch & 127)) << 11) +
                      (token0 & 2047);
        ushort4 pk;
        pk.x = f2bf(acc[mi][nj][0]);
        pk.y = f2bf(acc[mi][nj][1]);
        pk.z = f2bf(acc[mi][nj][2]);
        pk.w = f2bf(acc[mi][nj][3]);
        *(ushort4*)(Cb + base) = pk;
      }
    }
  }
#undef ASLOT
#undef BSLOT
#undef STAGE_A
#undef STAGE_B
#undef FRAG
#undef SYNC_MID
}

// ---------------- RMSNorm over rows of 512, in place (bf16) ---------------------------
__global__ __launch_bounds__(256) void rmsnorm_kernel(u16* __restrict__ t,
                                                      const u16* __restrict__ w) {
  int row = blockIdx.x * 4 + (threadIdx.x >> 6);
  int lane = threadIdx.x & 63;
  u16* xr = t + (size_t)row * 512;
  float v[8];
  float ss = 0.f;
  for (int i = 0; i < 8; ++i) {
    v[i] = bf2f(xr[lane + i * 64]);
    ss += v[i] * v[i];
  }
  for (int d = 32; d > 0; d >>= 1) ss += __shfl_xor(ss, d);
  float r = rsqrtf(ss * (1.f / 512.f) + 1e-6f);
  for (int i = 0; i < 8; ++i) xr[lane + i * 64] = f2bf(v[i] * r * bf2f(w[lane + i * 64]));
}

// ---------------- Flash attention (causal), bf16 MFMA, log2-domain softmax ------------
// q PRE-SCALED by (1/sqrt(128))*log2e => scores are log2-domain; exp via v_exp_f32.
// k: (B,S,H*128). vt: (B,H,128,S). o: (B,S,H*128).
// Row sums via ones-column MFMA; deferred-max (THR=8 log2).
__global__ __launch_bounds__(256) void attn_kernel(const u16* __restrict__ q,
                                                   const u16* __restrict__ k,
                                                   const u16* __restrict__ vt,
                                                   u16* __restrict__ o) {
  const int S = 2048;
  __shared__ __align__(16) u16 Kt[64 * 128];   // [key][chunk8 ^ (key&15)]
  __shared__ __align__(16) u16 Vt[128 * 64];   // [d][granule8 ^ (d&7)]
  __shared__ __align__(16) u16 P[4][16][64];   // [row][granule8 ^ (row&7)]
  const int t = threadIdx.x;
  const int w = t >> 6, lane = t & 63;
  const int quad = lane >> 4, l16 = lane & 15;
  const int bh = blockIdx.x;
  const int b = bh >> 4, h = bh & 15;
  const int qb = (int)gridDim.y - 1 - (int)blockIdx.y;  // heaviest first
  const int q0 = qb * 64 + w * 16;

  const u16* qbase = q + ((size_t)(b * S + q0 + l16)) * 2048 + h * 128;
  bf16x8 qf[4];
  for (int c = 0; c < 4; ++c) qf[c] = *(const bf16x8*)(qbase + c * 32 + quad * 8);

  const u16* kbase = k + (size_t)b * S * 2048 + h * 128;
  const u16* vtb = vt + (size_t)bh * 128 * S;

  const int ksrow = t >> 4, ksc = t & 15;  // K staging decode
  const int vsrow = t >> 3, vsc = t & 7;   // V staging decode

  bf16x8 onesf;  // B-operand of the row-sum MFMA: all 1.0 bf16
#pragma unroll
  for (int i = 0; i < 8; ++i) onesf[i] = (short)0x3F80;

  float m_i[4], l_i[4];
  floatx4 acc[8];
  for (int r = 0; r < 4; ++r) { m_i[r] = -1e30f; l_i[r] = 0.f; }
  for (int nd = 0; nd < 8; ++nd) acc[nd] = (floatx4){0.f, 0.f, 0.f, 0.f};

  const int kmax = q0 + 15;
  const int qbase64 = qb * 64;
  for (int kb = 0; kb <= qbase64; kb += 64) {
    const bool diag = (kb == qbase64);
    __syncthreads();
    for (int j = 0; j < 4; ++j) {
      int row = j * 16 + ksrow;
      GLOAD_LDS16(kbase + (size_t)(kb + row) * 2048 + (ksc ^ (row & 15)) * 8,
                  Kt + (size_t)(row * 16 + ksc) * 8);
    }
    for (int j = 0; j < 4; ++j) {
      int row = j * 32 + vsrow;
      GLOAD_LDS16(vtb + (size_t)row * S + kb + ((vsc ^ (row & 7)) * 8),
                  Vt + (size_t)(row * 8 + vsc) * 8);
    }
    __syncthreads();

    floatx4 s[4];
    if (!diag) {
      for (int ns = 0; ns < 4; ++ns) {
        s[ns] = (floatx4){0.f, 0.f, 0.f, 0.f};
        for (int c = 0; c < 4; ++c) {
          bf16x8 kf = *(const bf16x8*)&Kt[(ns * 16 + l16) * 128 + ((c * 4 + quad) ^ l16) * 8];
          s[ns] = __builtin_amdgcn_mfma_f32_16x16x32_bf16(qf[c], kf, s[ns], 0, 0, 0);
        }
      }
    } else {
      for (int ns = 0; ns < 4; ++ns) {
        if (kb + ns * 16 <= kmax) {
          s[ns] = (floatx4){0.f, 0.f, 0.f, 0.f};
          for (int c = 0; c < 4; ++c) {
            bf16x8 kf = *(const bf16x8*)&Kt[(ns * 16 + l16) * 128 + ((c * 4 + quad) ^ l16) * 8];
            s[ns] = __builtin_amdgcn_mfma_f32_16x16x32_bf16(qf[c], kf, s[ns], 0, 0, 0);
          }
          int key = kb + ns * 16 + l16;
          for (int r = 0; r < 4; ++r)
            s[ns][r] = (key > q0 + quad * 4 + r) ? -1e30f : s[ns][r];
        } else {
          s[ns] = (floatx4){-1e30f, -1e30f, -1e30f, -1e30f};
        }
      }
    }
    float tmax[4];
    for (int r = 0; r < 4; ++r) {
      float v = fmaxf(fmaxf(s[0][r], s[1][r]), fmaxf(s[2][r], s[3][r]));
      for (int d = 1; d < 16; d <<= 1) v = fmaxf(v, __shfl_xor(v, d));
      tmax[r] = v;
    }
    bool grow = (tmax[0] > m_i[0] + 8.f) || (tmax[1] > m_i[1] + 8.f) ||
                (tmax[2] > m_i[2] + 8.f) || (tmax[3] > m_i[3] + 8.f);
    if (__any(grow)) {
      for (int r = 0; r < 4; ++r) {
        float mn = fmaxf(m_i[r], tmax[r]);
        float alpha = exp2fast(m_i[r] - mn);
        m_i[r] = mn;
        l_i[r] *= alpha;
        for (int nd = 0; nd < 8; ++nd) acc[nd][r] *= alpha;
      }
    }
    for (int ns = 0; ns < 4; ++ns)
      for (int r = 0; r < 4; ++r) s[ns][r] = exp2fast(s[ns][r] - m_i[r]);
    for (int ns = 0; ns < 4; ++ns)
      for (int r = 0; r < 4; ++r) {
        int row = quad * 4 + r;
        P[w][row][(((ns * 2 + (l16 >> 3)) ^ (row & 7)) << 3) | (l16 & 7)] = f2bf_hu(s[ns][r]);
      }
    floatx4 ls = (floatx4){0.f, 0.f, 0.f, 0.f};
    for (int kc = 0; kc < 2; ++kc) {
      if (!diag || kb + kc * 32 <= kmax) {
        bf16x8 pa = *(const bf16x8*)&P[w][l16][((kc * 4 + quad) ^ (l16 & 7)) * 8];
        ls = __builtin_amdgcn_mfma_f32_16x16x32_bf16(pa, onesf, ls, 0, 0, 0);
        for (int nd = 0; nd < 8; ++nd) {
          int d = nd * 16 + l16;
          bf16x8 vf = *(const bf16x8*)&Vt[(d * 8 + ((kc * 4 + quad) ^ (d & 7))) * 8];
          acc[nd] = __builtin_amdgcn_mfma_f32_16x16x32_bf16(pa, vf, acc[nd], 0, 0, 0);
        }
      }
    }
    for (int r = 0; r < 4; ++r) l_i[r] += ls[r];
  }
  u16* ob = o + ((size_t)(b * S + q0 + quad * 4)) * 2048 + h * 128;
  for (int r = 0; r < 4; ++r) {
    float inv = 1.f / l_i[r];
    for (int nd = 0; nd < 8; ++nd)
      ob[(size_t)r * 2048 + nd * 16 + l16] = f2bf(acc[nd][r] * inv);
  }
}

// ------------------------------------ launcher ---------------------------------------
extern "C" void kernel_launch(void* const* d_in, const int* in_sizes, int n_in,
                              void* d_out, int out_size, void* d_ws, size_t ws_size,
                              hipStream_t stream) {
  const void* x    = d_in[0];  // (2,2048,2048)
  const void* fcos = d_in[1];  // (2048,64)
  const void* fsin = d_in[2];
  const void* wkv  = d_in[3];  // (2048,512)
  const void* wnr  = d_in[4];  // (512,)
  const void* wku  = d_in[5];  // (512,2048)
  const void* wvu  = d_in[6];  // (512,2048)
  const void* wq   = d_in[7];  // (2048,2048)
  const void* wo   = d_in[8];  // (2048,2048)
  const u16* probe = (const u16*)fcos;

  const size_t MB = 1u << 20;
  char* ws = (char*)d_ws;
  u16* xc    = (u16*)(ws);             // 16 MiB x bf16; dead after fused Q+KV
  u16* vtb   = (u16*)(ws);             //   ... then V^T (B,H,128,S), written by K+V gemm
  u16* qb    = (u16*)(ws + 16 * MB);   // 16 MiB q (rope'd, pre-scaled); dead after attn
  u16* kb    = (u16*)(ws + 32 * MB);   // 16 MiB k (rope'd)
  u16* ab    = (u16*)(ws + 48 * MB);   // 16 MiB attention output
  u16* lat   = (u16*)(ws + 64 * MB);   // 4 MiB kv latent
  u16* wqT   = (u16*)(ws + 68 * MB);   // 8 MiB; contiguous with wkvT -> fused B [2560,2048]
  u16* woT   = (u16*)(ws + 68 * MB);   //   ... then w_out^T (after Q+KV gemm)
  u16* wkvT  = (u16*)(ws + 76 * MB);   // 2 MiB
  u16* wkT   = (u16*)(ws + 78 * MB);   // 2 MiB; contiguous with wvT -> fused B [4096,512]
  u16* wvT   = (u16*)(ws + 80 * MB);   // 2 MiB
  u16* fcosc = (u16*)(ws + 82 * MB);   // 256 KiB
  u16* fsinc = (u16*)(ws + 82 * MB + 256 * 1024);
  u16* wnrc  = (u16*)(ws + 82 * MB + 512 * 1024);  // 1 KiB  (total < 83 MiB)

  // 1/sqrt(128) * log2(e): softmax runs in log2 domain (v_exp_f32 = 2^x)
  const float QSCALE = 0.08838834764831845f * 1.4426950408889634f;
  dim3 blk(256);

  // --- convert inputs to bf16 (identity copy if already bf16) ---
  cvt_to_bf16<<<dim3(4096), blk, 0, stream>>>(x, xc, 8388608, probe);
  cvt_to_bf16<<<dim3(64), blk, 0, stream>>>(fcos, fcosc, 131072, probe);
  cvt_to_bf16<<<dim3(64), blk, 0, stream>>>(fsin, fsinc, 131072, probe);
  cvt_to_bf16<<<dim3(1), blk, 0, stream>>>(wnr, wnrc, 512, probe);

  // --- weight transposes for the fused Q+KV gemm (B rows: wqT then wkvT, contiguous) --
  transpose_cvt<<<dim3(64, 64), blk, 0, stream>>>(wq, wqT, 2048, 2048, probe);
  transpose_cvt<<<dim3(16, 64), blk, 0, stream>>>(wkv, wkvT, 2048, 512, probe);

  // --- fused Q (rope, pre-scaled) + KV-compress: M=4096, N=2560, K=2048 (640 blocks) --
  gemm128<<<dim3(20, 32), dim3(512), 0, stream>>>(xc, wqT, qb, 2048, lat, 512,
                                                  2560, 2048, 2048, 1,
                                                  fcosc, fsinc, QSCALE, probe);
  rmsnorm_kernel<<<dim3(1024), blk, 0, stream>>>(lat, wnrc);

  // --- fused K (rope) + V (direct V^T scatter): M=4096, N=4096, K=512 (1024 blocks) ---
  transpose_cvt<<<dim3(64, 16), blk, 0, stream>>>(wku, wkT, 512, 2048, probe);
  transpose_cvt<<<dim3(64, 16), blk, 0, stream>>>(wvu, wvT, 512, 2048, probe);
  gemm128<<<dim3(32, 32), dim3(512), 0, stream>>>(lat, wkT, kb, 2048, vtb, 0,
                                                  4096, 512, 2048, 2,
                                                  fcosc, fsinc, 1.0f, probe);

  // --- w_out^T into dead wqT slot ---
  transpose_cvt<<<dim3(64, 64), blk, 0, stream>>>(wo, woT, 2048, 2048, probe);

  // --- causal flash attention (2D grid, heaviest qb dispatched first) ---
  attn_kernel<<<dim3(32, 32), blk, 0, stream>>>(qb, kb, vtb, ab);

  // --- output projection straight into d_out: M=4096, N=2048, K=2048 (512 blocks) -----
  gemm128<<<dim3(16, 32), dim3(512), 0, stream>>>(ab, woT, d_out, 2048, nullptr, 0,
                                                  2048, 2048, 0, 0,
                                                  nullptr, nullptr, 1.0f, probe);
}

// Round 6
// 364.167 us; speedup vs baseline: 1.2267x; 1.0211x over previous
//
#include <hip/hip_runtime.h>

typedef unsigned short u16;
typedef __attribute__((ext_vector_type(8))) short bf16x8;   // 8 bf16 = 4 VGPRs (MFMA A/B frag)
typedef __attribute__((ext_vector_type(4))) float floatx4;  // MFMA C/D frag

__device__ __forceinline__ float bf2f(u16 h) {
  return __uint_as_float(((unsigned int)h) << 16);
}
__device__ __forceinline__ u16 f2bf(float f) {
  unsigned int u = __float_as_uint(f);
  u += 0x7fffu + ((u >> 16) & 1u);  // RNE
  return (u16)(u >> 16);
}
// cheaper round-half-up (same 0.5 ulp bound) for the attention P pack
__device__ __forceinline__ u16 f2bf_hu(float f) {
  return (u16)((__float_as_uint(f) + 0x8000u) >> 16);
}
// raw v_exp_f32: computes 2^x (softmax runs in log2 domain; log2e folded into Q scale)
__device__ __forceinline__ float exp2fast(float x) {
  float r;
  asm("v_exp_f32 %0, %1" : "=v"(r) : "v"(x));
  return r;
}
// probe[0] is freqs_cos[0] == 1.0f: fp32 low u16 = 0x0000, bf16 = 0x3F80.
__device__ __forceinline__ bool is_f32(const u16* probe) { return probe[0] == 0; }

// async global->LDS, 16B per lane. LDS dest must be wave-uniform base + lane*16.
#define GLOAD_LDS16(gsrc, ldst)                                                        \
  __builtin_amdgcn_global_load_lds(                                                    \
      (const __attribute__((address_space(1))) unsigned int*)(gsrc),                   \
      (__attribute__((address_space(3))) unsigned int*)(ldst), 16, 0, 0)

// ------------- convert any input buffer (fp32 or bf16 per probe) -> bf16 --------------
__global__ __launch_bounds__(256) void cvt_to_bf16(const void* __restrict__ in,
                                                   u16* __restrict__ out, int n,
                                                   const u16* __restrict__ probe) {
  int i = (blockIdx.x * 256 + threadIdx.x) * 8;
  if (i >= n) return;
  if (is_f32(probe)) {
    const float* f = (const float*)in;
    uint4 o;
    o.x = (unsigned)f2bf(f[i + 0]) | ((unsigned)f2bf(f[i + 1]) << 16);
    o.y = (unsigned)f2bf(f[i + 2]) | ((unsigned)f2bf(f[i + 3]) << 16);
    o.z = (unsigned)f2bf(f[i + 4]) | ((unsigned)f2bf(f[i + 5]) << 16);
    o.w = (unsigned)f2bf(f[i + 6]) | ((unsigned)f2bf(f[i + 7]) << 16);
    *(uint4*)(out + i) = o;
  } else {
    *(uint4*)(out + i) = *(const uint4*)((const u16*)in + i);
  }
}

// ---------- transpose+convert: in (R,C) fp32/bf16 per probe -> out (C,R) bf16 ---------
__global__ __launch_bounds__(256) void transpose_cvt(const void* __restrict__ in,
                                                     u16* __restrict__ out,
                                                     int R, int C,
                                                     const u16* __restrict__ probe) {
  __shared__ u16 tile[32][33];
  int bx = blockIdx.x * 32;  // input col base
  int by = blockIdx.y * 32;  // input row base
  int tx = threadIdx.x & 31, ty = threadIdx.x >> 5;  // 32 x 8
  if (is_f32(probe)) {
    const float* f = (const float*)in;
    for (int i = 0; i < 32; i += 8)
      tile[ty + i][tx] = f2bf(f[(size_t)(by + ty + i) * C + (bx + tx)]);
  } else {
    const u16* u = (const u16*)in;
    for (int i = 0; i < 32; i += 8)
      tile[ty + i][tx] = u[(size_t)(by + ty + i) * C + (bx + tx)];
  }
  __syncthreads();
  for (int i = 0; i < 32; i += 8)
    out[(size_t)(bx + ty + i) * R + (by + tx)] = tile[tx][ty + i];
}

// ============ 128x128 8-wave pipelined GEMM, 64 KiB LDS -> 2 blocks/CU ================
// C = A[M,K] * BT[N,K]^T.  BK=64 in two 32-halves; 2 phases per K-tile, 8 MFMA each.
// (structure frozen from round 5; see r5 header comment for the hazard derivation)
__global__ __launch_bounds__(512, 4) void gemm128(const u16* __restrict__ A,
                                                  const u16* __restrict__ BT,
                                                  void* __restrict__ Ca, int sa,
                                                  u16* __restrict__ Cb, int sb,
                                                  int N, int K, int nsplit, int mode,
                                                  const u16* __restrict__ fc,
                                                  const u16* __restrict__ fs,
                                                  float oscale,
                                                  const u16* __restrict__ probe) {
  __shared__ __align__(16) u16 lds[32768];        // 64 KiB: A 2x2 slots, B 2x2 slots
  u16* const AsB = lds;                           // 4 slots x 4096 u16 (128 x 32)
  u16* const BsB = lds + 16384;
#define ASLOT(b, k) (AsB + ((((b) << 1) | (k)) << 12))
#define BSLOT(b, k) (BsB + ((((b) << 1) | (k)) << 12))

  const int t = threadIdx.x;
  const int lane = t & 63, wid = t >> 6;
  const int quad = lane >> 4, l16 = lane & 15;
  const int wr = wid >> 2, wc = wid & 3;          // 2 x 4 wave grid; wave owns 64x32
  const int m0 = blockIdx.y * 128, n0 = blockIdx.x * 128;
  const int NT = K >> 6;                          // K >= 512 in all our calls

  const u16* const Abase = A + (size_t)m0 * K;
  const u16* const Bbase = BT + (size_t)n0 * K;

  // staging decode: half-tile (128 rows x 32 k) = 8 KiB = 1 issue per thread
  const int rw = t >> 2;                          // row 0..127
  const int sg = (t & 3) ^ ((rw & 3) ^ ((rw >> 2) & 3));
  const u16* const sA = Abase + (size_t)rw * K + sg * 8;
  const u16* const sB = Bbase + (size_t)rw * K + sg * 8;
#define STAGE_A(slot, kb) GLOAD_LDS16(sA + (kb), (slot) + t * 8)
#define STAGE_B(slot, kb) GLOAD_LDS16(sB + (kb), (slot) + t * 8)

  // frag read: row base multiples of 16 contribute 0 to the swizzle
  const int gofs = (quad ^ ((l16 & 3) ^ ((l16 >> 2) & 3))) * 8;
#define FRAG(slot, row) (*(const bf16x8*)((slot) + (row) * 32 + gofs))

#define SYNC_MID()                                          \
  __builtin_amdgcn_s_barrier();                             \
  asm volatile("s_waitcnt lgkmcnt(0)" ::: "memory");        \
  __builtin_amdgcn_sched_barrier(0)

  floatx4 acc[4][2];
#pragma unroll
  for (int i = 0; i < 4; ++i)
#pragma unroll
    for (int j = 0; j < 2; ++j) acc[i][j] = (floatx4){0.f, 0.f, 0.f, 0.f};

  // ---- prologue: tile0 k0,k1 -> buf0; tile1 k0 -> buf1 (6 issues) ----
  STAGE_A(ASLOT(0, 0), 0);
  STAGE_B(BSLOT(0, 0), 0);
  STAGE_A(ASLOT(0, 1), 32);
  STAGE_B(BSLOT(0, 1), 32);
  STAGE_A(ASLOT(1, 0), 64);
  STAGE_B(BSLOT(1, 0), 64);
  asm volatile("s_waitcnt vmcnt(2)" ::: "memory");  // tile0 fully landed
  __builtin_amdgcn_s_barrier();

  bf16x8 af[4], bfr[2];
  const int arow = wr * 64 + l16;   // + mi*16
  const int brow = wc * 32 + l16;   // + nj*16

#pragma unroll 1
  for (int u = 0; u < NT; ++u) {
    const int cur = u & 1, oth = cur ^ 1;
    const bool s1 = (u + 1 < NT), s2 = (u + 2 < NT);
    const int kb1 = (u + 1) << 6, kb2 = (u + 2) << 6;

    // ---------------- phase 1: k-half 0 ----------------
#pragma unroll
    for (int mi = 0; mi < 4; ++mi) af[mi] = FRAG(ASLOT(cur, 0), arow + mi * 16);
#pragma unroll
    for (int nj = 0; nj < 2; ++nj) bfr[nj] = FRAG(BSLOT(cur, 0), brow + nj * 16);
    if (s1) {
      STAGE_A(ASLOT(oth, 1), kb1 + 32);
      STAGE_B(BSLOT(oth, 1), kb1 + 32);
    }
    SYNC_MID();
    __builtin_amdgcn_s_setprio(1);
#pragma unroll
    for (int mi = 0; mi < 4; ++mi)
#pragma unroll
      for (int nj = 0; nj < 2; ++nj)
        acc[mi][nj] = __builtin_amdgcn_mfma_f32_16x16x32_bf16(af[mi], bfr[nj], acc[mi][nj], 0, 0, 0);
    __builtin_amdgcn_s_setprio(0);
    __builtin_amdgcn_sched_barrier(0);
    __builtin_amdgcn_s_barrier();

    // ---------------- phase 2: k-half 1 ----------------
#pragma unroll
    for (int mi = 0; mi < 4; ++mi) af[mi] = FRAG(ASLOT(cur, 1), arow + mi * 16);
#pragma unroll
    for (int nj = 0; nj < 2; ++nj) bfr[nj] = FRAG(BSLOT(cur, 1), brow + nj * 16);
    if (s2) {
      STAGE_A(ASLOT(cur, 0), kb2);
      STAGE_B(BSLOT(cur, 0), kb2);
    }
    SYNC_MID();
    __builtin_amdgcn_s_setprio(1);
#pragma unroll
    for (int mi = 0; mi < 4; ++mi)
#pragma unroll
      for (int nj = 0; nj < 2; ++nj)
        acc[mi][nj] = __builtin_amdgcn_mfma_f32_16x16x32_bf16(af[mi], bfr[nj], acc[mi][nj], 0, 0, 0);
    __builtin_amdgcn_s_setprio(0);
    __builtin_amdgcn_sched_barrier(0);
    if (s2)
      asm volatile("s_waitcnt vmcnt(2)" ::: "memory");  // retire thru (u+1).k1
    else
      asm volatile("s_waitcnt vmcnt(0)" ::: "memory");  // tail drain
    __builtin_amdgcn_s_barrier();
  }

  // ---------------- epilogue ----------------
  if (mode == 0) {
    const bool f32o = is_f32(probe);
#pragma unroll
    for (int mi = 0; mi < 4; ++mi) {
      int rbase = m0 + wr * 64 + mi * 16 + quad * 4;
#pragma unroll
      for (int nj = 0; nj < 2; ++nj) {
        int col = n0 + wc * 32 + nj * 16 + l16;
        if (f32o) {
          float* Cf = (float*)Ca;
          for (int r = 0; r < 4; ++r) Cf[(size_t)(rbase + r) * sa + col] = acc[mi][nj][r];
        } else {
          u16* Ch = (u16*)Ca;
          for (int r = 0; r < 4; ++r) Ch[(size_t)(rbase + r) * sa + col] = f2bf(acc[mi][nj][r]);
        }
      }
    }
  } else if (n0 < nsplit) {
    // RoPE epilogue: col pairs live in adjacent lanes (head dim 128 aligns to tile)
    const bool odd = (l16 & 1);
    u16* Ch = (u16*)Ca;
#pragma unroll
    for (int mi = 0; mi < 4; ++mi) {
      int rbase = m0 + wr * 64 + mi * 16 + quad * 4;
#pragma unroll
      for (int nj = 0; nj < 2; ++nj) {
        int col = n0 + wc * 32 + nj * 16 + l16;
        int p = (col & 127) >> 1;  // pair index within head (0..63)
        for (int r = 0; r < 4; ++r) {
          int srow = (rbase + r) & 2047;  // token index (M = B*2048)
          float c = bf2f(fc[srow * 64 + p]);
          float sn = bf2f(fs[srow * 64 + p]);
          float v = acc[mi][nj][r];
          float pv = __shfl_xor(v, 1);
          float o = fmaf(v, c, odd ? pv * sn : -pv * sn);
          Ch[(size_t)(rbase + r) * sa + col] = f2bf(o * oscale);
        }
      }
    }
  } else if (mode == 1) {
    // plain bf16 into Cb
#pragma unroll
    for (int mi = 0; mi < 4; ++mi) {
      int rbase = m0 + wr * 64 + mi * 16 + quad * 4;
#pragma unroll
      for (int nj = 0; nj < 2; ++nj) {
        int col = n0 - nsplit + wc * 32 + nj * 16 + l16;
        for (int r = 0; r < 4; ++r)
          Cb[(size_t)(rbase + r) * sb + col] = f2bf(acc[mi][nj][r]);
      }
    }
  } else {
    // V^T scatter: Cb is (B,H,128,S); 4 tokens contiguous per lane -> ushort4
#pragma unroll
    for (int mi = 0; mi < 4; ++mi) {
      int token0 = m0 + wr * 64 + mi * 16 + quad * 4;  // same b for r=0..3
#pragma unroll
      for (int nj = 0; nj < 2; ++nj) {
        int ch = n0 - nsplit + wc * 32 + nj * 16 + l16;  // h*128 + d
        size_t base = (((size_t)((token0 >> 11) * 16 + (ch >> 7)) * 128 + (ch & 127)) << 11) +
                      (token0 & 2047);
        ushort4 pk;
        pk.x = f2bf(acc[mi][nj][0]);
        pk.y = f2bf(acc[mi][nj][1]);
        pk.z = f2bf(acc[mi][nj][2]);
        pk.w = f2bf(acc[mi][nj][3]);
        *(ushort4*)(Cb + base) = pk;
      }
    }
  }
#undef ASLOT
#undef BSLOT
#undef STAGE_A
#undef STAGE_B
#undef FRAG
#undef SYNC_MID
}

// ---------------- RMSNorm over rows of 512, in place (bf16) ---------------------------
__global__ __launch_bounds__(256) void rmsnorm_kernel(u16* __restrict__ t,
                                                      const u16* __restrict__ w) {
  int row = blockIdx.x * 4 + (threadIdx.x >> 6);
  int lane = threadIdx.x & 63;
  u16* xr = t + (size_t)row * 512;
  float v[8];
  float ss = 0.f;
  for (int i = 0; i < 8; ++i) {
    v[i] = bf2f(xr[lane + i * 64]);
    ss += v[i] * v[i];
  }
  for (int d = 32; d > 0; d >>= 1) ss += __shfl_xor(ss, d);
  float r = rsqrtf(ss * (1.f / 512.f) + 1e-6f);
  for (int i = 0; i < 8; ++i) xr[lane + i * 64] = f2bf(v[i] * r * bf2f(w[lane + i * 64]));
}

// ---------------- Flash attention (causal), bf16 MFMA, log2-domain softmax ------------
// q PRE-SCALED by (1/sqrt(128))*log2e => scores are log2-domain; exp via v_exp_f32.
// k: (B,S,H*128). vt: (B,H,128,S). o: (B,S,H*128).
// Row sums via ones-column MFMA; deferred-max (THR=8 log2).
// PAIR-BALANCED grid: block (bh, j) processes q-tiles {31-j, j} sequentially ->
// every block does exactly 33 K-tile iterations. Mapping-agnostic perfect balance
// (r5 counters: 21% avg occupancy = makespan tail of the variable-work 1024-block
// grid where all blocks were co-resident with no backfill).
__global__ __launch_bounds__(256) void attn_kernel(const u16* __restrict__ q,
                                                   const u16* __restrict__ k,
                                                   const u16* __restrict__ vt,
                                                   u16* __restrict__ o) {
  const int S = 2048;
  __shared__ __align__(16) u16 Kt[64 * 128];   // [key][chunk8 ^ (key&15)]
  __shared__ __align__(16) u16 Vt[128 * 64];   // [d][granule8 ^ (d&7)]
  __shared__ __align__(16) u16 P[4][16][64];   // [row][granule8 ^ (row&7)]
  const int t = threadIdx.x;
  const int w = t >> 6, lane = t & 63;
  const int quad = lane >> 4, l16 = lane & 15;
  const int bh = blockIdx.x;
  const int b = bh >> 4, h = bh & 15;

  const u16* kbase = k + (size_t)b * S * 2048 + h * 128;
  const u16* vtb = vt + (size_t)bh * 128 * S;

  const int ksrow = t >> 4, ksc = t & 15;  // K staging decode
  const int vsrow = t >> 3, vsc = t & 7;   // V staging decode

  bf16x8 onesf;  // B-operand of the row-sum MFMA: all 1.0 bf16
#pragma unroll
  for (int i = 0; i < 8; ++i) onesf[i] = (short)0x3F80;

  // two q-tiles, heavy first: total work (32-j) + (j+1) = 33 tiles for every block
  const int qb0 = 31 - (int)blockIdx.y;
  const int qb1 = (int)blockIdx.y;

#pragma unroll 1
  for (int qi = 0; qi < 2; ++qi) {
    const int qb = qi ? qb1 : qb0;
    const int q0 = qb * 64 + w * 16;

    // Q fragments (A layout: m=l16, k=quad*8+j), 4 dim-chunks of 32
    const u16* qbase = q + ((size_t)(b * S + q0 + l16)) * 2048 + h * 128;
    bf16x8 qf[4];
    for (int c = 0; c < 4; ++c) qf[c] = *(const bf16x8*)(qbase + c * 32 + quad * 8);

    float m_i[4], l_i[4];
    floatx4 acc[8];
    for (int r = 0; r < 4; ++r) { m_i[r] = -1e30f; l_i[r] = 0.f; }
    for (int nd = 0; nd < 8; ++nd) acc[nd] = (floatx4){0.f, 0.f, 0.f, 0.f};

    const int kmax = q0 + 15;
    const int qbase64 = qb * 64;
    for (int kb = 0; kb <= qbase64; kb += 64) {
      const bool diag = (kb == qbase64);
      __syncthreads();  // all waves done reading Kt/Vt from previous step
      for (int j = 0; j < 4; ++j) {
        int row = j * 16 + ksrow;
        GLOAD_LDS16(kbase + (size_t)(kb + row) * 2048 + (ksc ^ (row & 15)) * 8,
                    Kt + (size_t)(row * 16 + ksc) * 8);
      }
      for (int j = 0; j < 4; ++j) {
        int row = j * 32 + vsrow;
        GLOAD_LDS16(vtb + (size_t)row * S + kb + ((vsc ^ (row & 7)) * 8),
                    Vt + (size_t)(row * 8 + vsc) * 8);
      }
      __syncthreads();  // staging drained

      floatx4 s[4];
      if (!diag) {
        for (int ns = 0; ns < 4; ++ns) {
          s[ns] = (floatx4){0.f, 0.f, 0.f, 0.f};
          for (int c = 0; c < 4; ++c) {
            bf16x8 kf = *(const bf16x8*)&Kt[(ns * 16 + l16) * 128 + ((c * 4 + quad) ^ l16) * 8];
            s[ns] = __builtin_amdgcn_mfma_f32_16x16x32_bf16(qf[c], kf, s[ns], 0, 0, 0);
          }
        }
      } else {
        for (int ns = 0; ns < 4; ++ns) {
          if (kb + ns * 16 <= kmax) {
            s[ns] = (floatx4){0.f, 0.f, 0.f, 0.f};
            for (int c = 0; c < 4; ++c) {
              bf16x8 kf = *(const bf16x8*)&Kt[(ns * 16 + l16) * 128 + ((c * 4 + quad) ^ l16) * 8];
              s[ns] = __builtin_amdgcn_mfma_f32_16x16x32_bf16(qf[c], kf, s[ns], 0, 0, 0);
            }
            int key = kb + ns * 16 + l16;
            for (int r = 0; r < 4; ++r)
              s[ns][r] = (key > q0 + quad * 4 + r) ? -1e30f : s[ns][r];
          } else {
            s[ns] = (floatx4){-1e30f, -1e30f, -1e30f, -1e30f};
          }
        }
      }
      float tmax[4];
      for (int r = 0; r < 4; ++r) {
        float v = fmaxf(fmaxf(s[0][r], s[1][r]), fmaxf(s[2][r], s[3][r]));
        for (int d = 1; d < 16; d <<= 1) v = fmaxf(v, __shfl_xor(v, d));
        tmax[r] = v;
      }
      bool grow = (tmax[0] > m_i[0] + 8.f) || (tmax[1] > m_i[1] + 8.f) ||
                  (tmax[2] > m_i[2] + 8.f) || (tmax[3] > m_i[3] + 8.f);
      if (__any(grow)) {
        for (int r = 0; r < 4; ++r) {
          float mn = fmaxf(m_i[r], tmax[r]);
          float alpha = exp2fast(m_i[r] - mn);
          m_i[r] = mn;
          l_i[r] *= alpha;
          for (int nd = 0; nd < 8; ++nd) acc[nd][r] *= alpha;
        }
      }
      for (int ns = 0; ns < 4; ++ns)
        for (int r = 0; r < 4; ++r) s[ns][r] = exp2fast(s[ns][r] - m_i[r]);
      for (int ns = 0; ns < 4; ++ns)
        for (int r = 0; r < 4; ++r) {
          int row = quad * 4 + r;
          P[w][row][(((ns * 2 + (l16 >> 3)) ^ (row & 7)) << 3) | (l16 & 7)] = f2bf_hu(s[ns][r]);
        }
      floatx4 ls = (floatx4){0.f, 0.f, 0.f, 0.f};
      for (int kc = 0; kc < 2; ++kc) {
        if (!diag || kb + kc * 32 <= kmax) {
          bf16x8 pa = *(const bf16x8*)&P[w][l16][((kc * 4 + quad) ^ (l16 & 7)) * 8];
          ls = __builtin_amdgcn_mfma_f32_16x16x32_bf16(pa, onesf, ls, 0, 0, 0);
          for (int nd = 0; nd < 8; ++nd) {
            int d = nd * 16 + l16;
            bf16x8 vf = *(const bf16x8*)&Vt[(d * 8 + ((kc * 4 + quad) ^ (d & 7))) * 8];
            acc[nd] = __builtin_amdgcn_mfma_f32_16x16x32_bf16(pa, vf, acc[nd], 0, 0, 0);
          }
        }
      }
      for (int r = 0; r < 4; ++r) l_i[r] += ls[r];
    }
    // ---- epilogue for this q-tile ----
    u16* ob = o + ((size_t)(b * S + q0 + quad * 4)) * 2048 + h * 128;
    for (int r = 0; r < 4; ++r) {
      float inv = 1.f / l_i[r];
      for (int nd = 0; nd < 8; ++nd)
        ob[(size_t)r * 2048 + nd * 16 + l16] = f2bf(acc[nd][r] * inv);
    }
  }
}

// ------------------------------------ launcher ---------------------------------------
extern "C" void kernel_launch(void* const* d_in, const int* in_sizes, int n_in,
                              void* d_out, int out_size, void* d_ws, size_t ws_size,
                              hipStream_t stream) {
  const void* x    = d_in[0];  // (2,2048,2048)
  const void* fcos = d_in[1];  // (2048,64)
  const void* fsin = d_in[2];
  const void* wkv  = d_in[3];  // (2048,512)
  const void* wnr  = d_in[4];  // (512,)
  const void* wku  = d_in[5];  // (512,2048)
  const void* wvu  = d_in[6];  // (512,2048)
  const void* wq   = d_in[7];  // (2048,2048)
  const void* wo   = d_in[8];  // (2048,2048)
  const u16* probe = (const u16*)fcos;

  const size_t MB = 1u << 20;
  char* ws = (char*)d_ws;
  u16* xc    = (u16*)(ws);             // 16 MiB x bf16; dead after fused Q+KV
  u16* vtb   = (u16*)(ws);             //   ... then V^T (B,H,128,S), written by K+V gemm
  u16* qb    = (u16*)(ws + 16 * MB);   // 16 MiB q (rope'd, pre-scaled); dead after attn
  u16* kb    = (u16*)(ws + 32 * MB);   // 16 MiB k (rope'd)
  u16* ab    = (u16*)(ws + 48 * MB);   // 16 MiB attention output
  u16* lat   = (u16*)(ws + 64 * MB);   // 4 MiB kv latent
  u16* wqT   = (u16*)(ws + 68 * MB);   // 8 MiB; contiguous with wkvT -> fused B [2560,2048]
  u16* woT   = (u16*)(ws + 68 * MB);   //   ... then w_out^T (after Q+KV gemm)
  u16* wkvT  = (u16*)(ws + 76 * MB);   // 2 MiB
  u16* wkT   = (u16*)(ws + 78 * MB);   // 2 MiB; contiguous with wvT -> fused B [4096,512]
  u16* wvT   = (u16*)(ws + 80 * MB);   // 2 MiB
  u16* fcosc = (u16*)(ws + 82 * MB);   // 256 KiB
  u16* fsinc = (u16*)(ws + 82 * MB + 256 * 1024);
  u16* wnrc  = (u16*)(ws + 82 * MB + 512 * 1024);  // 1 KiB  (total < 83 MiB)

  // 1/sqrt(128) * log2(e): softmax runs in log2 domain (v_exp_f32 = 2^x)
  const float QSCALE = 0.08838834764831845f * 1.4426950408889634f;
  dim3 blk(256);

  // --- convert inputs to bf16 (identity copy if already bf16) ---
  cvt_to_bf16<<<dim3(4096), blk, 0, stream>>>(x, xc, 8388608, probe);
  cvt_to_bf16<<<dim3(64), blk, 0, stream>>>(fcos, fcosc, 131072, probe);
  cvt_to_bf16<<<dim3(64), blk, 0, stream>>>(fsin, fsinc, 131072, probe);
  cvt_to_bf16<<<dim3(1), blk, 0, stream>>>(wnr, wnrc, 512, probe);

  // --- weight transposes for the fused Q+KV gemm (B rows: wqT then wkvT, contiguous) --
  transpose_cvt<<<dim3(64, 64), blk, 0, stream>>>(wq, wqT, 2048, 2048, probe);
  transpose_cvt<<<dim3(16, 64), blk, 0, stream>>>(wkv, wkvT, 2048, 512, probe);

  // --- fused Q (rope, pre-scaled) + KV-compress: M=4096, N=2560, K=2048 (640 blocks) --
  gemm128<<<dim3(20, 32), dim3(512), 0, stream>>>(xc, wqT, qb, 2048, lat, 512,
                                                  2560, 2048, 2048, 1,
                                                  fcosc, fsinc, QSCALE, probe);
  rmsnorm_kernel<<<dim3(1024), blk, 0, stream>>>(lat, wnrc);

  // --- fused K (rope) + V (direct V^T scatter): M=4096, N=4096, K=512 (1024 blocks) ---
  transpose_cvt<<<dim3(64, 16), blk, 0, stream>>>(wku, wkT, 512, 2048, probe);
  transpose_cvt<<<dim3(64, 16), blk, 0, stream>>>(wvu, wvT, 512, 2048, probe);
  gemm128<<<dim3(32, 32), dim3(512), 0, stream>>>(lat, wkT, kb, 2048, vtb, 0,
                                                  4096, 512, 2048, 2,
                                                  fcosc, fsinc, 1.0f, probe);

  // --- w_out^T into dead wqT slot ---
  transpose_cvt<<<dim3(64, 64), blk, 0, stream>>>(wo, woT, 2048, 2048, probe);

  // --- causal flash attention (pair-balanced: 512 blocks x 33 tiles each) ---
  attn_kernel<<<dim3(32, 16), blk, 0, stream>>>(qb, kb, vtb, ab);

  // --- output projection straight into d_out: M=4096, N=2048, K=2048 (512 blocks) -----
  gemm128<<<dim3(16, 32), dim3(512), 0, stream>>>(ab, woT, d_out, 2048, nullptr, 0,
                                                  2048, 2048, 0, 0,
                                                  nullptr, nullptr, 1.0f, probe);
}